// Round 7
// baseline (265.848 us; speedup 1.0000x reference)
//
#include <hip/hip_runtime.h>
#include <hip/hip_bf16.h>

#define N_NODES 50000
#define N_EDGES 600000
#define HID     128
#define NG      500
#define NB_SCAN 196   // ceil(50000/256)
#define EB      2345  // ceil(600000/256) + 1 extra block for w3lin
#define HSTP    65    // padded LDS leading dim

// ---------------- degree count + pos (+ last block computes w3lin = W3@Wlin) ----------------

__global__ void k_count(const int* __restrict__ dst, int* __restrict__ cnt,
                        int* __restrict__ pos,
                        const float* __restrict__ W3, const float* __restrict__ Wlin,
                        const float* __restrict__ b3, const float* __restrict__ blin,
                        float* __restrict__ w3buf) {
    if (blockIdx.x == EB - 1) {
        int t = threadIdx.x;          // 256 threads -> 128x2
        int k = t >> 1, j = t & 1;
        float acc = 0.f;
        for (int m = 0; m < 128; m++) acc += W3[k * 128 + m] * Wlin[m * 2 + j];
        w3buf[k * 2 + j] = acc;
        if (t < 2) {
            float c = 0.f;
            for (int m = 0; m < 128; m++) c += b3[m] * Wlin[m * 2 + t];
            w3buf[256 + t] = c + blin[t];   // const added to every non-empty graph
            w3buf[258 + t] = blin[t];       // empty-graph fallback
        }
        return;
    }
    int e = blockIdx.x * 256 + threadIdx.x;
    if (e < N_EDGES) pos[e] = atomicAdd(&cnt[dst[e]], 1);
}

__global__ void k_blocksum(const int* __restrict__ cnt, int* __restrict__ bsum) {
    __shared__ int s[256];
    int i = blockIdx.x * 256 + threadIdx.x;
    s[threadIdx.x] = (i < N_NODES) ? cnt[i] : 0;
    __syncthreads();
    for (int o = 128; o; o >>= 1) {
        if (threadIdx.x < o) s[threadIdx.x] += s[threadIdx.x + o];
        __syncthreads();
    }
    if (threadIdx.x == 0) bsum[blockIdx.x] = s[0];
}

__global__ void k_scanbsum(int* __restrict__ bsum) {
    int lane = threadIdx.x;            // 64 lanes
    int v[4];
    int base = lane * 4;
    for (int j = 0; j < 4; j++) v[j] = (base + j < NB_SCAN) ? bsum[base + j] : 0;
    int tot = v[0] + v[1] + v[2] + v[3];
    int inc = tot;
    for (int o = 1; o < 64; o <<= 1) {
        int u = __shfl_up(inc, o);
        if (lane >= o) inc += u;
    }
    int run = inc - tot;
    for (int j = 0; j < 4; j++) {
        if (base + j < NB_SCAN) bsum[base + j] = run;
        run += v[j];
    }
}

// finalize rowptr + dinv + xd (= x*dinv)
__global__ void k_rowptr(const int* __restrict__ cnt, const int* __restrict__ bsum,
                         const float* __restrict__ x,
                         int* __restrict__ rowptr, float* __restrict__ dinv,
                         float* __restrict__ xd) {
    __shared__ int s[256];
    int i = blockIdx.x * 256 + threadIdx.x;
    int c = (i < N_NODES) ? cnt[i] : 0;
    s[threadIdx.x] = c;
    __syncthreads();
    for (int o = 1; o < 256; o <<= 1) {
        int v = (threadIdx.x >= o) ? s[threadIdx.x - o] : 0;
        __syncthreads();
        s[threadIdx.x] += v;
        __syncthreads();
    }
    if (i < N_NODES) {
        int incl = s[threadIdx.x];
        rowptr[i] = bsum[blockIdx.x] + incl - c;
        float di = rsqrtf((float)c + 1.0f);
        dinv[i] = di;
        xd[i] = x[i] * di;
        if (i == N_NODES - 1) rowptr[N_NODES] = bsum[blockIdx.x] + incl;
    }
}

// CSR fill — no atomics, independent per edge
__global__ void k_fill(const int* __restrict__ src, const int* __restrict__ dst,
                       const int* __restrict__ rowptr, const int* __restrict__ pos,
                       int* __restrict__ csr) {
    int e = blockIdx.x * 256 + threadIdx.x;
    if (e < N_EDGES) {
        int d = dst[e];
        csr[rowptr[d] + pos[e]] = src[e];
    }
}

// layer-1 scalar aggregate via CSR gather: s1d[i] = {x_i*di^2 + (Σ xd[j])*di, di}
__global__ void k_s1d(const float* __restrict__ x, const float* __restrict__ xd,
                      const float* __restrict__ dinv, const int* __restrict__ rowptr,
                      const int* __restrict__ csr, float2* __restrict__ s1d) {
    int i = blockIdx.x * 256 + threadIdx.x;
    if (i >= N_NODES) return;
    float di = dinv[i];
    int e0 = rowptr[i], e1 = rowptr[i + 1];
    float acc = 0.f;
    int e = e0;
    for (; e + 3 < e1; e += 4)
        acc += xd[csr[e]] + xd[csr[e+1]] + xd[csr[e+2]] + xd[csr[e+3]];
    for (; e < e1; e++) acc += xd[csr[e]];
    float2 r = {x[i] * di * di + acc * di, di};
    s1d[i] = r;
}

// ---------------- Fused: reconstruct-aggregate g=A·h1 (broadcast gathers), GEMM g@W2,
// relu+b2, ·w3lin -> z[N,2].  h1[j][c] = relu(s1[j]*W1[c]+b1[c]); never materialized.

__global__ __launch_bounds__(256) void k_gemm_fused(const float2* __restrict__ s1d,
                                                    const int* __restrict__ rowptr,
                                                    const int* __restrict__ csr,
                                                    const float* __restrict__ W1,
                                                    const float* __restrict__ b1,
                                                    const float* __restrict__ W2,
                                                    const float* __restrict__ b2,
                                                    const float* __restrict__ w3buf,
                                                    float* __restrict__ z) {
    __shared__ float Ws[128 * 64];     // 32 KB
    __shared__ float HsT[128 * HSTP];  // 33.3 KB, [k][r] padded (conflict-free stores)
    int t = threadIdx.x;
    int r0 = blockIdx.x * 64;
    int c4  = t & 31;     // channel lane; owns channels c4 + 32m, m=0..3
    int sub = t >> 5;     // node subgroup 0..7

    float w1r[4], b1r[4];
    #pragma unroll
    for (int m = 0; m < 4; m++) { w1r[m] = W1[c4 + 32*m]; b1r[m] = b1[c4 + 32*m]; }

    // Phase A: per-node (32-lane group) reconstruct-aggregate, broadcast gathers
    for (int rr = sub; rr < 64; rr += 8) {
        int node = r0 + rr;
        float ga[4] = {0.f, 0.f, 0.f, 0.f};
        if (node < N_NODES) {
            float2 sd = s1d[node];
            float di = sd.y, wself = sd.y * sd.y;
            #pragma unroll
            for (int m = 0; m < 4; m++) ga[m] = fmaxf(sd.x * w1r[m] + b1r[m], 0.f) * wself;
            int e0 = rowptr[node], e1 = rowptr[node + 1];
            int e = e0;
            for (; e + 1 < e1; e += 2) {
                int j0 = csr[e], j1 = csr[e + 1];
                float2 sj0 = s1d[j0], sj1 = s1d[j1];
                float wj0 = sj0.y * di, wj1 = sj1.y * di;
                #pragma unroll
                for (int m = 0; m < 4; m++) {
                    ga[m] += fmaxf(sj0.x * w1r[m] + b1r[m], 0.f) * wj0
                           + fmaxf(sj1.x * w1r[m] + b1r[m], 0.f) * wj1;
                }
            }
            if (e < e1) {
                int j0 = csr[e];
                float2 sj0 = s1d[j0];
                float wj0 = sj0.y * di;
                #pragma unroll
                for (int m = 0; m < 4; m++)
                    ga[m] += fmaxf(sj0.x * w1r[m] + b1r[m], 0.f) * wj0;
            }
        }
        #pragma unroll
        for (int m = 0; m < 4; m++) HsT[(c4 + 32*m) * HSTP + rr] = ga[m];
    }

    // stage W2 col-half 0
    for (int p = 0; p < 8; p++) {
        int elem = t * 4 + p * 1024;
        int k = elem >> 6, cc = elem & 63;
        *(float4*)&Ws[elem] = *(const float4*)&W2[k * 128 + cc];
    }
    __syncthreads();

    int col = (t & 15) * 4;
    int row = (t >> 4) * 4;
    float a0[4][4] = {}, a1[4][4] = {};
    #pragma unroll 4
    for (int k = 0; k < 128; k++) {
        float4 w = *(float4*)&Ws[k * 64 + col];
        float4 h = *(float4*)&HsT[k * HSTP + row];
        a0[0][0] += h.x * w.x; a0[0][1] += h.x * w.y; a0[0][2] += h.x * w.z; a0[0][3] += h.x * w.w;
        a0[1][0] += h.y * w.x; a0[1][1] += h.y * w.y; a0[1][2] += h.y * w.z; a0[1][3] += h.y * w.w;
        a0[2][0] += h.z * w.x; a0[2][1] += h.z * w.y; a0[2][2] += h.z * w.z; a0[2][3] += h.z * w.w;
        a0[3][0] += h.w * w.x; a0[3][1] += h.w * w.y; a0[3][2] += h.w * w.z; a0[3][3] += h.w * w.w;
    }
    __syncthreads();
    // stage W2 col-half 1
    for (int p = 0; p < 8; p++) {
        int elem = t * 4 + p * 1024;
        int k = elem >> 6, cc = elem & 63;
        *(float4*)&Ws[elem] = *(const float4*)&W2[k * 128 + 64 + cc];
    }
    __syncthreads();
    #pragma unroll 4
    for (int k = 0; k < 128; k++) {
        float4 w = *(float4*)&Ws[k * 64 + col];
        float4 h = *(float4*)&HsT[k * HSTP + row];
        a1[0][0] += h.x * w.x; a1[0][1] += h.x * w.y; a1[0][2] += h.x * w.z; a1[0][3] += h.x * w.w;
        a1[1][0] += h.y * w.x; a1[1][1] += h.y * w.y; a1[1][2] += h.y * w.z; a1[1][3] += h.y * w.w;
        a1[2][0] += h.z * w.x; a1[2][1] += h.z * w.y; a1[2][2] += h.z * w.z; a1[2][3] += h.z * w.w;
        a1[3][0] += h.w * w.x; a1[3][1] += h.w * w.y; a1[3][2] += h.w * w.z; a1[3][3] += h.w * w.w;
    }

    // epilogue: relu(+b2), project to 2 outputs, reduce across 16 lanes of row group
    float b2a[4], b2b[4], w0a[4], w1a[4], w0b[4], w1b[4];
    #pragma unroll
    for (int c = 0; c < 4; c++) {
        b2a[c] = b2[col + c];        b2b[c] = b2[64 + col + c];
        w0a[c] = w3buf[(col + c) * 2 + 0];      w1a[c] = w3buf[(col + c) * 2 + 1];
        w0b[c] = w3buf[(64 + col + c) * 2 + 0]; w1b[c] = w3buf[(64 + col + c) * 2 + 1];
    }
    #pragma unroll
    for (int r = 0; r < 4; r++) {
        float p0 = 0.f, p1 = 0.f;
        #pragma unroll
        for (int c = 0; c < 4; c++) {
            float v0 = fmaxf(a0[r][c] + b2a[c], 0.f);
            float v1 = fmaxf(a1[r][c] + b2b[c], 0.f);
            p0 += v0 * w0a[c] + v1 * w0b[c];
            p1 += v0 * w1a[c] + v1 * w1b[c];
        }
        for (int o = 1; o < 16; o <<= 1) { p0 += __shfl_xor(p0, o); p1 += __shfl_xor(p1, o); }
        int rg = r0 + row + r;
        if ((t & 15) == 0 && rg < N_NODES) { z[rg * 2 + 0] = p0; z[rg * 2 + 1] = p1; }
    }
}

// ---------------- Layer-3 aggregation on z (2-wide) + atomic pool ----------------

__global__ void k_aggz(const float* __restrict__ z, const int* __restrict__ rowptr,
                       const int* __restrict__ csr, const float* __restrict__ dinv,
                       const int* __restrict__ batch, float* __restrict__ pool) {
    int i = blockIdx.x * 256 + threadIdx.x;
    if (i >= N_NODES) return;
    const float2* Z = (const float2*)z;
    float di = dinv[i];
    float2 zi = Z[i];
    float a0 = zi.x * di * di, a1 = zi.y * di * di;
    int e0 = rowptr[i], e1 = rowptr[i + 1];
    int e = e0;
    for (; e + 3 < e1; e += 4) {
        int s0 = csr[e], s1 = csr[e+1], s2 = csr[e+2], s3 = csr[e+3];
        float w0 = dinv[s0]*di, w1 = dinv[s1]*di, w2 = dinv[s2]*di, w3 = dinv[s3]*di;
        float2 za = Z[s0], zb = Z[s1], zc = Z[s2], zd = Z[s3];
        a0 += za.x*w0 + zb.x*w1 + zc.x*w2 + zd.x*w3;
        a1 += za.y*w0 + zb.y*w1 + zc.y*w2 + zd.y*w3;
    }
    for (; e < e1; e++) {
        int s = csr[e];
        float w = dinv[s] * di;
        float2 za = Z[s];
        a0 += za.x * w; a1 += za.y * w;
    }
    int g = batch[i];
    atomicAdd(&pool[g * 2 + 0], a0);
    atomicAdd(&pool[g * 2 + 1], a1);
}

// ---------------- Final: mean + consts (batch sorted; counts via binary search) ----------------

__global__ __launch_bounds__(256) void k_final3(const float* __restrict__ pool,
                                                const int* __restrict__ batch,
                                                const float* __restrict__ w3buf,
                                                float* __restrict__ out) {
    int g = blockIdx.x * 256 + threadIdx.x;
    if (g >= NG) return;
    int lo = 0, hi = N_NODES;
    while (lo < hi) { int mid = (lo + hi) >> 1; if (batch[mid] < g) lo = mid + 1; else hi = mid; }
    int start = lo;
    hi = N_NODES;
    while (lo < hi) { int mid = (lo + hi) >> 1; if (batch[mid] < g + 1) lo = mid + 1; else hi = mid; }
    int end = lo;
    if (end > start) {
        float inv = 1.0f / (float)(end - start);
        out[g * 2 + 0] = pool[g * 2 + 0] * inv + w3buf[256];
        out[g * 2 + 1] = pool[g * 2 + 1] * inv + w3buf[257];
    } else {
        out[g * 2 + 0] = w3buf[258];
        out[g * 2 + 1] = w3buf[259];
    }
}

// ---------------- launch ----------------

extern "C" void kernel_launch(void* const* d_in, const int* in_sizes, int n_in,
                              void* d_out, int out_size, void* d_ws, size_t ws_size,
                              hipStream_t stream) {
    const float* x    = (const float*)d_in[0];
    const float* W1   = (const float*)d_in[1];
    const float* b1   = (const float*)d_in[2];
    const float* W2   = (const float*)d_in[3];
    const float* b2   = (const float*)d_in[4];
    const float* W3   = (const float*)d_in[5];
    const float* b3   = (const float*)d_in[6];
    const float* Wlin = (const float*)d_in[7];
    const float* blin = (const float*)d_in[8];
    const int*   eidx = (const int*)d_in[9];
    const int*   batch= (const int*)d_in[10];
    const int* esrc = eidx;
    const int* edst = eidx + N_EDGES;
    float* out = (float*)d_out;

    char* w = (char*)d_ws;
    size_t off = 0;
    auto alloc = [&](size_t bytes) { size_t o = off; off = (off + bytes + 255) & ~(size_t)255; return o; };
    // cnt and pool adjacent -> one memset zeroes both
    size_t cnt_off = alloc(N_NODES * 4);
    int*   cnt    = (int*)  (w + cnt_off);
    float* pool   = (float*)(w + alloc(NG * 2 * 4));
    size_t zero_bytes = off - cnt_off;
    int*   rowptr = (int*)  (w + alloc((N_NODES + 1) * 4));
    int*   csr    = (int*)  (w + alloc(N_EDGES * 4));
    int*   pos    = (int*)  (w + alloc(N_EDGES * 4));
    float* dinv   = (float*)(w + alloc(N_NODES * 4));
    float* xd     = (float*)(w + alloc(N_NODES * 4));
    float2* s1d   = (float2*)(w + alloc((size_t)N_NODES * 8));
    int*   bsum   = (int*)  (w + alloc(NB_SCAN * 4));
    float* w3buf  = (float*)(w + alloc(260 * 4));
    float* z      = (float*)(w + alloc((size_t)N_NODES * 2 * 4));

    const int FB = (N_EDGES + 255) / 256;   // 2344
    // 1: zero cnt + pool
    hipMemsetAsync(cnt, 0, zero_bytes, stream);
    // 2: degree count + pos + w3lin precompute (extra block)
    k_count<<<EB, 256, 0, stream>>>(edst, cnt, pos, W3, Wlin, b3, blin, w3buf);
    // 3-5: prefix scan -> rowptr, dinv, xd
    k_blocksum<<<NB_SCAN, 256, 0, stream>>>(cnt, bsum);
    k_scanbsum<<<1, 64, 0, stream>>>(bsum);
    k_rowptr<<<NB_SCAN, 256, 0, stream>>>(cnt, bsum, x, rowptr, dinv, xd);
    // 6: CSR fill (atomic-free)
    k_fill<<<FB, 256, 0, stream>>>(esrc, edst, rowptr, pos, csr);
    // 7: layer-1 scalar aggregate (gather, atomic-free)
    k_s1d<<<NB_SCAN, 256, 0, stream>>>(x, xd, dinv, rowptr, csr, s1d);
    // 8: fused reconstruct + GEMM + relu + projection -> z [N,2]
    k_gemm_fused<<<(N_NODES + 63) / 64, 256, 0, stream>>>(s1d, rowptr, csr,
                                                          W1, b1, W2, b2, w3buf, z);
    // 9: layer-3 2-wide aggregation + atomic pool
    k_aggz<<<NB_SCAN, 256, 0, stream>>>(z, rowptr, csr, dinv, batch, pool);
    // 10: mean + consts
    k_final3<<<2, 256, 0, stream>>>(pool, batch, w3buf, out);
}

// Round 8
// 234.951 us; speedup vs baseline: 1.1315x; 1.1315x over previous
//
#include <hip/hip_runtime.h>
#include <hip/hip_bf16.h>

#define N_NODES 50000
#define N_EDGES 600000
#define HID     128
#define NG      500
#define NB_SCAN 196   // ceil(50000/256)
#define EB      2345  // ceil(600000/256) + 1 extra block for w3lin

// ---------------- degree count + pos (+ last block computes w3lin = W3@Wlin) ----------------

__global__ void k_count(const int* __restrict__ dst, int* __restrict__ cnt,
                        int* __restrict__ pos,
                        const float* __restrict__ W3, const float* __restrict__ Wlin,
                        const float* __restrict__ b3, const float* __restrict__ blin,
                        float* __restrict__ w3buf) {
    if (blockIdx.x == EB - 1) {
        int t = threadIdx.x;          // 256 threads -> 128x2
        int k = t >> 1, j = t & 1;
        float acc = 0.f;
        for (int m = 0; m < 128; m++) acc += W3[k * 128 + m] * Wlin[m * 2 + j];
        w3buf[k * 2 + j] = acc;
        if (t < 2) {
            float c = 0.f;
            for (int m = 0; m < 128; m++) c += b3[m] * Wlin[m * 2 + t];
            w3buf[256 + t] = c + blin[t];   // const added to every non-empty graph
            w3buf[258 + t] = blin[t];       // empty-graph fallback
        }
        return;
    }
    int e = blockIdx.x * 256 + threadIdx.x;
    if (e < N_EDGES) pos[e] = atomicAdd(&cnt[dst[e]], 1);
}

__global__ void k_blocksum(const int* __restrict__ cnt, int* __restrict__ bsum) {
    __shared__ int s[256];
    int i = blockIdx.x * 256 + threadIdx.x;
    s[threadIdx.x] = (i < N_NODES) ? cnt[i] : 0;
    __syncthreads();
    for (int o = 128; o; o >>= 1) {
        if (threadIdx.x < o) s[threadIdx.x] += s[threadIdx.x + o];
        __syncthreads();
    }
    if (threadIdx.x == 0) bsum[blockIdx.x] = s[0];
}

__global__ void k_scanbsum(int* __restrict__ bsum) {
    int lane = threadIdx.x;            // 64 lanes
    int v[4];
    int base = lane * 4;
    for (int j = 0; j < 4; j++) v[j] = (base + j < NB_SCAN) ? bsum[base + j] : 0;
    int tot = v[0] + v[1] + v[2] + v[3];
    int inc = tot;
    for (int o = 1; o < 64; o <<= 1) {
        int u = __shfl_up(inc, o);
        if (lane >= o) inc += u;
    }
    int run = inc - tot;
    for (int j = 0; j < 4; j++) {
        if (base + j < NB_SCAN) bsum[base + j] = run;
        run += v[j];
    }
}

// finalize rowptr + dinv + xd (= x*dinv)
__global__ void k_rowptr(const int* __restrict__ cnt, const int* __restrict__ bsum,
                         const float* __restrict__ x,
                         int* __restrict__ rowptr, float* __restrict__ dinv,
                         float* __restrict__ xd) {
    __shared__ int s[256];
    int i = blockIdx.x * 256 + threadIdx.x;
    int c = (i < N_NODES) ? cnt[i] : 0;
    s[threadIdx.x] = c;
    __syncthreads();
    for (int o = 1; o < 256; o <<= 1) {
        int v = (threadIdx.x >= o) ? s[threadIdx.x - o] : 0;
        __syncthreads();
        s[threadIdx.x] += v;
        __syncthreads();
    }
    if (i < N_NODES) {
        int incl = s[threadIdx.x];
        rowptr[i] = bsum[blockIdx.x] + incl - c;
        float di = rsqrtf((float)c + 1.0f);
        dinv[i] = di;
        xd[i] = x[i] * di;
        if (i == N_NODES - 1) rowptr[N_NODES] = bsum[blockIdx.x] + incl;
    }
}

// CSR fill — no atomics, independent per edge
__global__ void k_fill(const int* __restrict__ src, const int* __restrict__ dst,
                       const int* __restrict__ rowptr, const int* __restrict__ pos,
                       int* __restrict__ csr) {
    int e = blockIdx.x * 256 + threadIdx.x;
    if (e < N_EDGES) {
        int d = dst[e];
        csr[rowptr[d] + pos[e]] = src[e];
    }
}

// layer-1 scalar aggregate via CSR gather: s1d[i] = {x_i*di^2 + (Σ xd[j])*di, di}
__global__ void k_s1d(const float* __restrict__ x, const float* __restrict__ xd,
                      const float* __restrict__ dinv, const int* __restrict__ rowptr,
                      const int* __restrict__ csr, float2* __restrict__ s1d) {
    int i = blockIdx.x * 256 + threadIdx.x;
    if (i >= N_NODES) return;
    float di = dinv[i];
    int e0 = rowptr[i], e1 = rowptr[i + 1];
    float acc = 0.f;
    int e = e0;
    for (; e + 3 < e1; e += 4)
        acc += xd[csr[e]] + xd[csr[e+1]] + xd[csr[e+2]] + xd[csr[e+3]];
    for (; e < e1; e++) acc += xd[csr[e]];
    float2 r = {x[i] * di * di + acc * di, di};
    s1d[i] = r;
}

// ---------------- Fused: reconstruct-aggregate g=A·h1, GEMM g@W2, relu+b2, ·w3lin -> z[N,2]
// Phase A layout (R6-proven): lane = node within 64-row tile, grp = 32-channel chunk.
// 64 independent gather streams per wave (MLP) beats broadcast-efficiency (R7 lesson).
// h1[j][c] = relu(s1[j]*W1[c]+b1[c]); h1/h2 never materialized.

__global__ __launch_bounds__(256) void k_gemm_fused(const float2* __restrict__ s1d,
                                                    const int* __restrict__ rowptr,
                                                    const int* __restrict__ csr,
                                                    const float* __restrict__ W1,
                                                    const float* __restrict__ b1,
                                                    const float* __restrict__ W2,
                                                    const float* __restrict__ b2,
                                                    const float* __restrict__ w3buf,
                                                    float* __restrict__ z) {
    __shared__ float Ws[128 * 64];    // 32 KB
    __shared__ float HsT[128 * 64];   // 32 KB, [k][r] stride-64 (verified conflict-free)
    int t = threadIdx.x;
    int r0 = blockIdx.x * 64;
    int lane = t & 63, grp = t >> 6;  // lane = row, grp = channel chunk (4 x 32)

    float w1r[32], b1r[32];
    #pragma unroll
    for (int kk = 0; kk < 32; kk++) { w1r[kk] = W1[grp * 32 + kk]; b1r[kk] = b1[grp * 32 + kk]; }

    float ga[32];
    #pragma unroll
    for (int kk = 0; kk < 32; kk++) ga[kk] = 0.f;
    int node = r0 + lane;
    if (node < N_NODES) {
        float2 sd = s1d[node];
        float di = sd.y, wself = sd.y * sd.y;
        #pragma unroll
        for (int kk = 0; kk < 32; kk++) ga[kk] = fmaxf(sd.x * w1r[kk] + b1r[kk], 0.f) * wself;
        int e0 = rowptr[node], e1 = rowptr[node + 1];
        int e = e0;
        for (; e + 1 < e1; e += 2) {
            int j0 = csr[e], j1 = csr[e + 1];
            float2 sj0 = s1d[j0], sj1 = s1d[j1];
            float wj0 = sj0.y * di, wj1 = sj1.y * di;
            #pragma unroll
            for (int kk = 0; kk < 32; kk++) {
                ga[kk] += fmaxf(sj0.x * w1r[kk] + b1r[kk], 0.f) * wj0
                        + fmaxf(sj1.x * w1r[kk] + b1r[kk], 0.f) * wj1;
            }
        }
        if (e < e1) {
            int j0 = csr[e];
            float2 sj0 = s1d[j0];
            float wj0 = sj0.y * di;
            #pragma unroll
            for (int kk = 0; kk < 32; kk++)
                ga[kk] += fmaxf(sj0.x * w1r[kk] + b1r[kk], 0.f) * wj0;
        }
    }
    #pragma unroll
    for (int kk = 0; kk < 32; kk++) HsT[(grp * 32 + kk) * 64 + lane] = ga[kk];

    // stage W2 col-half 0
    for (int p = 0; p < 8; p++) {
        int elem = t * 4 + p * 1024;
        int k = elem >> 6, cc = elem & 63;
        *(float4*)&Ws[elem] = *(const float4*)&W2[k * 128 + cc];
    }
    __syncthreads();

    int col = (t & 15) * 4;
    int row = (t >> 4) * 4;
    float a0[4][4] = {}, a1[4][4] = {};
    #pragma unroll 4
    for (int k = 0; k < 128; k++) {
        float4 w = *(float4*)&Ws[k * 64 + col];
        float4 h = *(float4*)&HsT[k * 64 + row];
        a0[0][0] += h.x * w.x; a0[0][1] += h.x * w.y; a0[0][2] += h.x * w.z; a0[0][3] += h.x * w.w;
        a0[1][0] += h.y * w.x; a0[1][1] += h.y * w.y; a0[1][2] += h.y * w.z; a0[1][3] += h.y * w.w;
        a0[2][0] += h.z * w.x; a0[2][1] += h.z * w.y; a0[2][2] += h.z * w.z; a0[2][3] += h.z * w.w;
        a0[3][0] += h.w * w.x; a0[3][1] += h.w * w.y; a0[3][2] += h.w * w.z; a0[3][3] += h.w * w.w;
    }
    __syncthreads();
    // stage W2 col-half 1
    for (int p = 0; p < 8; p++) {
        int elem = t * 4 + p * 1024;
        int k = elem >> 6, cc = elem & 63;
        *(float4*)&Ws[elem] = *(const float4*)&W2[k * 128 + 64 + cc];
    }
    __syncthreads();
    #pragma unroll 4
    for (int k = 0; k < 128; k++) {
        float4 w = *(float4*)&Ws[k * 64 + col];
        float4 h = *(float4*)&HsT[k * 64 + row];
        a1[0][0] += h.x * w.x; a1[0][1] += h.x * w.y; a1[0][2] += h.x * w.z; a1[0][3] += h.x * w.w;
        a1[1][0] += h.y * w.x; a1[1][1] += h.y * w.y; a1[1][2] += h.y * w.z; a1[1][3] += h.y * w.w;
        a1[2][0] += h.z * w.x; a1[2][1] += h.z * w.y; a1[2][2] += h.z * w.z; a1[2][3] += h.z * w.w;
        a1[3][0] += h.w * w.x; a1[3][1] += h.w * w.y; a1[3][2] += h.w * w.z; a1[3][3] += h.w * w.w;
    }

    // epilogue: relu(+b2), project to 2 outputs, reduce across 16 lanes of row group
    float b2a[4], b2b[4], w0a[4], w1a[4], w0b[4], w1b[4];
    #pragma unroll
    for (int c = 0; c < 4; c++) {
        b2a[c] = b2[col + c];        b2b[c] = b2[64 + col + c];
        w0a[c] = w3buf[(col + c) * 2 + 0];      w1a[c] = w3buf[(col + c) * 2 + 1];
        w0b[c] = w3buf[(64 + col + c) * 2 + 0]; w1b[c] = w3buf[(64 + col + c) * 2 + 1];
    }
    #pragma unroll
    for (int r = 0; r < 4; r++) {
        float p0 = 0.f, p1 = 0.f;
        #pragma unroll
        for (int c = 0; c < 4; c++) {
            float v0 = fmaxf(a0[r][c] + b2a[c], 0.f);
            float v1 = fmaxf(a1[r][c] + b2b[c], 0.f);
            p0 += v0 * w0a[c] + v1 * w0b[c];
            p1 += v0 * w1a[c] + v1 * w1b[c];
        }
        for (int o = 1; o < 16; o <<= 1) { p0 += __shfl_xor(p0, o); p1 += __shfl_xor(p1, o); }
        int rg = r0 + row + r;
        if ((t & 15) == 0 && rg < N_NODES) { z[rg * 2 + 0] = p0; z[rg * 2 + 1] = p1; }
    }
}

// ---------------- Layer-3 aggregation on z (2-wide) + atomic pool ----------------

__global__ void k_aggz(const float* __restrict__ z, const int* __restrict__ rowptr,
                       const int* __restrict__ csr, const float* __restrict__ dinv,
                       const int* __restrict__ batch, float* __restrict__ pool) {
    int i = blockIdx.x * 256 + threadIdx.x;
    if (i >= N_NODES) return;
    const float2* Z = (const float2*)z;
    float di = dinv[i];
    float2 zi = Z[i];
    float a0 = zi.x * di * di, a1 = zi.y * di * di;
    int e0 = rowptr[i], e1 = rowptr[i + 1];
    int e = e0;
    for (; e + 3 < e1; e += 4) {
        int s0 = csr[e], s1 = csr[e+1], s2 = csr[e+2], s3 = csr[e+3];
        float w0 = dinv[s0]*di, w1 = dinv[s1]*di, w2 = dinv[s2]*di, w3 = dinv[s3]*di;
        float2 za = Z[s0], zb = Z[s1], zc = Z[s2], zd = Z[s3];
        a0 += za.x*w0 + zb.x*w1 + zc.x*w2 + zd.x*w3;
        a1 += za.y*w0 + zb.y*w1 + zc.y*w2 + zd.y*w3;
    }
    for (; e < e1; e++) {
        int s = csr[e];
        float w = dinv[s] * di;
        float2 za = Z[s];
        a0 += za.x * w; a1 += za.y * w;
    }
    int g = batch[i];
    atomicAdd(&pool[g * 2 + 0], a0);
    atomicAdd(&pool[g * 2 + 1], a1);
}

// ---------------- Final: mean + consts (batch sorted; counts via binary search) ----------------

__global__ __launch_bounds__(256) void k_final3(const float* __restrict__ pool,
                                                const int* __restrict__ batch,
                                                const float* __restrict__ w3buf,
                                                float* __restrict__ out) {
    int g = blockIdx.x * 256 + threadIdx.x;
    if (g >= NG) return;
    int lo = 0, hi = N_NODES;
    while (lo < hi) { int mid = (lo + hi) >> 1; if (batch[mid] < g) lo = mid + 1; else hi = mid; }
    int start = lo;
    hi = N_NODES;
    while (lo < hi) { int mid = (lo + hi) >> 1; if (batch[mid] < g + 1) lo = mid + 1; else hi = mid; }
    int end = lo;
    if (end > start) {
        float inv = 1.0f / (float)(end - start);
        out[g * 2 + 0] = pool[g * 2 + 0] * inv + w3buf[256];
        out[g * 2 + 1] = pool[g * 2 + 1] * inv + w3buf[257];
    } else {
        out[g * 2 + 0] = w3buf[258];
        out[g * 2 + 1] = w3buf[259];
    }
}

// ---------------- launch ----------------

extern "C" void kernel_launch(void* const* d_in, const int* in_sizes, int n_in,
                              void* d_out, int out_size, void* d_ws, size_t ws_size,
                              hipStream_t stream) {
    const float* x    = (const float*)d_in[0];
    const float* W1   = (const float*)d_in[1];
    const float* b1   = (const float*)d_in[2];
    const float* W2   = (const float*)d_in[3];
    const float* b2   = (const float*)d_in[4];
    const float* W3   = (const float*)d_in[5];
    const float* b3   = (const float*)d_in[6];
    const float* Wlin = (const float*)d_in[7];
    const float* blin = (const float*)d_in[8];
    const int*   eidx = (const int*)d_in[9];
    const int*   batch= (const int*)d_in[10];
    const int* esrc = eidx;
    const int* edst = eidx + N_EDGES;
    float* out = (float*)d_out;

    char* w = (char*)d_ws;
    size_t off = 0;
    auto alloc = [&](size_t bytes) { size_t o = off; off = (off + bytes + 255) & ~(size_t)255; return o; };
    // cnt and pool adjacent -> one memset zeroes both
    size_t cnt_off = alloc(N_NODES * 4);
    int*   cnt    = (int*)  (w + cnt_off);
    float* pool   = (float*)(w + alloc(NG * 2 * 4));
    size_t zero_bytes = off - cnt_off;
    int*   rowptr = (int*)  (w + alloc((N_NODES + 1) * 4));
    int*   csr    = (int*)  (w + alloc(N_EDGES * 4));
    int*   pos    = (int*)  (w + alloc(N_EDGES * 4));
    float* dinv   = (float*)(w + alloc(N_NODES * 4));
    float* xd     = (float*)(w + alloc(N_NODES * 4));
    float2* s1d   = (float2*)(w + alloc((size_t)N_NODES * 8));
    int*   bsum   = (int*)  (w + alloc(NB_SCAN * 4));
    float* w3buf  = (float*)(w + alloc(260 * 4));
    float* z      = (float*)(w + alloc((size_t)N_NODES * 2 * 4));

    const int FB = (N_EDGES + 255) / 256;   // 2344
    // 1: zero cnt + pool
    hipMemsetAsync(cnt, 0, zero_bytes, stream);
    // 2: degree count + pos + w3lin precompute (extra block)
    k_count<<<EB, 256, 0, stream>>>(edst, cnt, pos, W3, Wlin, b3, blin, w3buf);
    // 3-5: prefix scan -> rowptr, dinv, xd
    k_blocksum<<<NB_SCAN, 256, 0, stream>>>(cnt, bsum);
    k_scanbsum<<<1, 64, 0, stream>>>(bsum);
    k_rowptr<<<NB_SCAN, 256, 0, stream>>>(cnt, bsum, x, rowptr, dinv, xd);
    // 6: CSR fill (atomic-free)
    k_fill<<<FB, 256, 0, stream>>>(esrc, edst, rowptr, pos, csr);
    // 7: layer-1 scalar aggregate (gather, atomic-free)
    k_s1d<<<NB_SCAN, 256, 0, stream>>>(x, xd, dinv, rowptr, csr, s1d);
    // 8: fused reconstruct + GEMM + relu + projection -> z [N,2]
    k_gemm_fused<<<(N_NODES + 63) / 64, 256, 0, stream>>>(s1d, rowptr, csr,
                                                          W1, b1, W2, b2, w3buf, z);
    // 9: layer-3 2-wide aggregation + atomic pool
    k_aggz<<<NB_SCAN, 256, 0, stream>>>(z, rowptr, csr, dinv, batch, pool);
    // 10: mean + consts
    k_final3<<<2, 256, 0, stream>>>(pool, batch, w3buf, out);
}

// Round 9
// 234.893 us; speedup vs baseline: 1.1318x; 1.0002x over previous
//
#include <hip/hip_runtime.h>
#include <hip/hip_bf16.h>

#define N_NODES 50000
#define N_EDGES 600000
#define HID     128
#define NG      500
#define NB_SCAN 196   // ceil(50000/256)
#define EB      2345  // ceil(600000/256) + 1 extra block for w3lin

// ---------------- degree count + pos (+ last block computes w3lin = W3@Wlin) ----------------

__global__ void k_count(const int* __restrict__ dst, int* __restrict__ cnt,
                        int* __restrict__ pos,
                        const float* __restrict__ W3, const float* __restrict__ Wlin,
                        const float* __restrict__ b3, const float* __restrict__ blin,
                        float* __restrict__ w3buf) {
    if (blockIdx.x == EB - 1) {
        int t = threadIdx.x;          // 256 threads -> 128x2
        int k = t >> 1, j = t & 1;
        float acc = 0.f;
        for (int m = 0; m < 128; m++) acc += W3[k * 128 + m] * Wlin[m * 2 + j];
        w3buf[k * 2 + j] = acc;
        if (t < 2) {
            float c = 0.f;
            for (int m = 0; m < 128; m++) c += b3[m] * Wlin[m * 2 + t];
            w3buf[256 + t] = c + blin[t];   // const added to every non-empty graph
            w3buf[258 + t] = blin[t];       // empty-graph fallback
        }
        return;
    }
    int e = blockIdx.x * 256 + threadIdx.x;
    if (e < N_EDGES) pos[e] = atomicAdd(&cnt[dst[e]], 1);
}

__global__ void k_blocksum(const int* __restrict__ cnt, int* __restrict__ bsum) {
    __shared__ int s[256];
    int i = blockIdx.x * 256 + threadIdx.x;
    s[threadIdx.x] = (i < N_NODES) ? cnt[i] : 0;
    __syncthreads();
    for (int o = 128; o; o >>= 1) {
        if (threadIdx.x < o) s[threadIdx.x] += s[threadIdx.x + o];
        __syncthreads();
    }
    if (threadIdx.x == 0) bsum[blockIdx.x] = s[0];
}

// rowptr + dinv + xd; per-block bsum prefix computed in-kernel (k_scanbsum merged away)
__global__ void k_rowptr(const int* __restrict__ cnt, const int* __restrict__ bsum,
                         const float* __restrict__ x,
                         int* __restrict__ rowptr, float* __restrict__ dinv,
                         float* __restrict__ xd) {
    __shared__ int s[256];
    __shared__ int base_sh;
    // exclusive prefix of bsum over blocks < blockIdx.x (196 entries, tree-reduce)
    int v = (threadIdx.x < (int)blockIdx.x && threadIdx.x < NB_SCAN) ? bsum[threadIdx.x] : 0;
    s[threadIdx.x] = v;
    __syncthreads();
    for (int o = 128; o; o >>= 1) {
        if (threadIdx.x < o) s[threadIdx.x] += s[threadIdx.x + o];
        __syncthreads();
    }
    if (threadIdx.x == 0) base_sh = s[0];
    __syncthreads();
    int base = base_sh;
    __syncthreads();

    int i = blockIdx.x * 256 + threadIdx.x;
    int c = (i < N_NODES) ? cnt[i] : 0;
    s[threadIdx.x] = c;
    __syncthreads();
    for (int o = 1; o < 256; o <<= 1) {
        int vv = (threadIdx.x >= o) ? s[threadIdx.x - o] : 0;
        __syncthreads();
        s[threadIdx.x] += vv;
        __syncthreads();
    }
    if (i < N_NODES) {
        int incl = s[threadIdx.x];
        rowptr[i] = base + incl - c;
        float di = rsqrtf((float)c + 1.0f);
        dinv[i] = di;
        xd[i] = x[i] * di;
        if (i == N_NODES - 1) rowptr[N_NODES] = base + incl;
    }
}

// CSR fill — no atomics, independent per edge
__global__ void k_fill(const int* __restrict__ src, const int* __restrict__ dst,
                       const int* __restrict__ rowptr, const int* __restrict__ pos,
                       int* __restrict__ csr) {
    int e = blockIdx.x * 256 + threadIdx.x;
    if (e < N_EDGES) {
        int d = dst[e];
        csr[rowptr[d] + pos[e]] = src[e];
    }
}

// layer-1 scalar aggregate via CSR gather: s1d[i] = {x_i*di^2 + (Σ xd[j])*di, di}
__global__ void k_s1d(const float* __restrict__ x, const float* __restrict__ xd,
                      const float* __restrict__ dinv, const int* __restrict__ rowptr,
                      const int* __restrict__ csr, float2* __restrict__ s1d) {
    int i = blockIdx.x * 256 + threadIdx.x;
    if (i >= N_NODES) return;
    float di = dinv[i];
    int e0 = rowptr[i], e1 = rowptr[i + 1];
    float acc = 0.f;
    int e = e0;
    for (; e + 3 < e1; e += 4)
        acc += xd[csr[e]] + xd[csr[e+1]] + xd[csr[e+2]] + xd[csr[e+3]];
    for (; e < e1; e++) acc += xd[csr[e]];
    float2 r = {x[i] * di * di + acc * di, di};
    s1d[i] = r;
}

// ---------------- Fused: reconstruct-aggregate g=A·h1, GEMM g@W2, relu+b2, ·w3lin -> z[N,2]
// Phase A: lane = node (64 independent gather streams/wave — R7 lesson), grp = 32-ch chunk.
// GEMM: W2 read directly from global (L2-resident, no Ws LDS) -> 32KB LDS -> 4 blocks/CU
// (vs 2 at 64KB), both column halves in one pass, single __syncthreads.

__global__ __launch_bounds__(256) void k_gemm_fused(const float2* __restrict__ s1d,
                                                    const int* __restrict__ rowptr,
                                                    const int* __restrict__ csr,
                                                    const float* __restrict__ W1,
                                                    const float* __restrict__ b1,
                                                    const float* __restrict__ W2,
                                                    const float* __restrict__ b2,
                                                    const float* __restrict__ w3buf,
                                                    float* __restrict__ z) {
    __shared__ float HsT[128 * 64];   // 32 KB, [k][r] stride-64 (verified conflict-free)
    int t = threadIdx.x;
    int r0 = blockIdx.x * 64;
    int lane = t & 63, grp = t >> 6;  // lane = row, grp = channel chunk (4 x 32)

    float w1r[32], b1r[32];
    #pragma unroll
    for (int kk = 0; kk < 32; kk++) { w1r[kk] = W1[grp * 32 + kk]; b1r[kk] = b1[grp * 32 + kk]; }

    float ga[32];
    #pragma unroll
    for (int kk = 0; kk < 32; kk++) ga[kk] = 0.f;
    int node = r0 + lane;
    if (node < N_NODES) {
        float2 sd = s1d[node];
        float di = sd.y, wself = sd.y * sd.y;
        #pragma unroll
        for (int kk = 0; kk < 32; kk++) ga[kk] = fmaxf(sd.x * w1r[kk] + b1r[kk], 0.f) * wself;
        int e0 = rowptr[node], e1 = rowptr[node + 1];
        int e = e0;
        for (; e + 3 < e1; e += 4) {
            int j0 = csr[e], j1 = csr[e+1], j2 = csr[e+2], j3 = csr[e+3];
            float2 s0 = s1d[j0], s1v = s1d[j1], s2 = s1d[j2], s3 = s1d[j3];
            float wj0 = s0.y * di, wj1 = s1v.y * di, wj2 = s2.y * di, wj3 = s3.y * di;
            #pragma unroll
            for (int kk = 0; kk < 32; kk++) {
                ga[kk] += fmaxf(s0.x  * w1r[kk] + b1r[kk], 0.f) * wj0
                        + fmaxf(s1v.x * w1r[kk] + b1r[kk], 0.f) * wj1
                        + fmaxf(s2.x  * w1r[kk] + b1r[kk], 0.f) * wj2
                        + fmaxf(s3.x  * w1r[kk] + b1r[kk], 0.f) * wj3;
            }
        }
        for (; e < e1; e++) {
            int j0 = csr[e];
            float2 sj0 = s1d[j0];
            float wj0 = sj0.y * di;
            #pragma unroll
            for (int kk = 0; kk < 32; kk++)
                ga[kk] += fmaxf(sj0.x * w1r[kk] + b1r[kk], 0.f) * wj0;
        }
    }
    #pragma unroll
    for (int kk = 0; kk < 32; kk++) HsT[(grp * 32 + kk) * 64 + lane] = ga[kk];
    __syncthreads();

    int col = (t & 15) * 4;
    int row = (t >> 4) * 4;
    float a0[4][4] = {}, a1[4][4] = {};
    #pragma unroll 4
    for (int k = 0; k < 128; k++) {
        float4 w0v = *(const float4*)&W2[k * 128 + col];
        float4 w1v = *(const float4*)&W2[k * 128 + 64 + col];
        float4 h   = *(float4*)&HsT[k * 64 + row];
        a0[0][0] += h.x * w0v.x; a0[0][1] += h.x * w0v.y; a0[0][2] += h.x * w0v.z; a0[0][3] += h.x * w0v.w;
        a0[1][0] += h.y * w0v.x; a0[1][1] += h.y * w0v.y; a0[1][2] += h.y * w0v.z; a0[1][3] += h.y * w0v.w;
        a0[2][0] += h.z * w0v.x; a0[2][1] += h.z * w0v.y; a0[2][2] += h.z * w0v.z; a0[2][3] += h.z * w0v.w;
        a0[3][0] += h.w * w0v.x; a0[3][1] += h.w * w0v.y; a0[3][2] += h.w * w0v.z; a0[3][3] += h.w * w0v.w;
        a1[0][0] += h.x * w1v.x; a1[0][1] += h.x * w1v.y; a1[0][2] += h.x * w1v.z; a1[0][3] += h.x * w1v.w;
        a1[1][0] += h.y * w1v.x; a1[1][1] += h.y * w1v.y; a1[1][2] += h.y * w1v.z; a1[1][3] += h.y * w1v.w;
        a1[2][0] += h.z * w1v.x; a1[2][1] += h.z * w1v.y; a1[2][2] += h.z * w1v.z; a1[2][3] += h.z * w1v.w;
        a1[3][0] += h.w * w1v.x; a1[3][1] += h.w * w1v.y; a1[3][2] += h.w * w1v.z; a1[3][3] += h.w * w1v.w;
    }

    // epilogue: relu(+b2), project to 2 outputs, reduce across 16 lanes of row group
    float b2a[4], b2b[4], w0a[4], w1a[4], w0b[4], w1b[4];
    #pragma unroll
    for (int c = 0; c < 4; c++) {
        b2a[c] = b2[col + c];        b2b[c] = b2[64 + col + c];
        w0a[c] = w3buf[(col + c) * 2 + 0];      w1a[c] = w3buf[(col + c) * 2 + 1];
        w0b[c] = w3buf[(64 + col + c) * 2 + 0]; w1b[c] = w3buf[(64 + col + c) * 2 + 1];
    }
    #pragma unroll
    for (int r = 0; r < 4; r++) {
        float p0 = 0.f, p1 = 0.f;
        #pragma unroll
        for (int c = 0; c < 4; c++) {
            float v0 = fmaxf(a0[r][c] + b2a[c], 0.f);
            float v1 = fmaxf(a1[r][c] + b2b[c], 0.f);
            p0 += v0 * w0a[c] + v1 * w0b[c];
            p1 += v0 * w1a[c] + v1 * w1b[c];
        }
        for (int o = 1; o < 16; o <<= 1) { p0 += __shfl_xor(p0, o); p1 += __shfl_xor(p1, o); }
        int rg = r0 + row + r;
        if ((t & 15) == 0 && rg < N_NODES) { z[rg * 2 + 0] = p0; z[rg * 2 + 1] = p1; }
    }
}

// ---------------- Layer-3 aggregation on z (2-wide) + atomic pool ----------------

__global__ void k_aggz(const float* __restrict__ z, const int* __restrict__ rowptr,
                       const int* __restrict__ csr, const float* __restrict__ dinv,
                       const int* __restrict__ batch, float* __restrict__ pool) {
    int i = blockIdx.x * 256 + threadIdx.x;
    if (i >= N_NODES) return;
    const float2* Z = (const float2*)z;
    float di = dinv[i];
    float2 zi = Z[i];
    float a0 = zi.x * di * di, a1 = zi.y * di * di;
    int e0 = rowptr[i], e1 = rowptr[i + 1];
    int e = e0;
    for (; e + 3 < e1; e += 4) {
        int s0 = csr[e], s1 = csr[e+1], s2 = csr[e+2], s3 = csr[e+3];
        float w0 = dinv[s0]*di, w1 = dinv[s1]*di, w2 = dinv[s2]*di, w3 = dinv[s3]*di;
        float2 za = Z[s0], zb = Z[s1], zc = Z[s2], zd = Z[s3];
        a0 += za.x*w0 + zb.x*w1 + zc.x*w2 + zd.x*w3;
        a1 += za.y*w0 + zb.y*w1 + zc.y*w2 + zd.y*w3;
    }
    for (; e < e1; e++) {
        int s = csr[e];
        float w = dinv[s] * di;
        float2 za = Z[s];
        a0 += za.x * w; a1 += za.y * w;
    }
    int g = batch[i];
    atomicAdd(&pool[g * 2 + 0], a0);
    atomicAdd(&pool[g * 2 + 1], a1);
}

// ---------------- Final: mean + consts (batch sorted; counts via binary search) ----------------

__global__ __launch_bounds__(256) void k_final3(const float* __restrict__ pool,
                                                const int* __restrict__ batch,
                                                const float* __restrict__ w3buf,
                                                float* __restrict__ out) {
    int g = blockIdx.x * 256 + threadIdx.x;
    if (g >= NG) return;
    int lo = 0, hi = N_NODES;
    while (lo < hi) { int mid = (lo + hi) >> 1; if (batch[mid] < g) lo = mid + 1; else hi = mid; }
    int start = lo;
    hi = N_NODES;
    while (lo < hi) { int mid = (lo + hi) >> 1; if (batch[mid] < g + 1) lo = mid + 1; else hi = mid; }
    int end = lo;
    if (end > start) {
        float inv = 1.0f / (float)(end - start);
        out[g * 2 + 0] = pool[g * 2 + 0] * inv + w3buf[256];
        out[g * 2 + 1] = pool[g * 2 + 1] * inv + w3buf[257];
    } else {
        out[g * 2 + 0] = w3buf[258];
        out[g * 2 + 1] = w3buf[259];
    }
}

// ---------------- launch ----------------

extern "C" void kernel_launch(void* const* d_in, const int* in_sizes, int n_in,
                              void* d_out, int out_size, void* d_ws, size_t ws_size,
                              hipStream_t stream) {
    const float* x    = (const float*)d_in[0];
    const float* W1   = (const float*)d_in[1];
    const float* b1   = (const float*)d_in[2];
    const float* W2   = (const float*)d_in[3];
    const float* b2   = (const float*)d_in[4];
    const float* W3   = (const float*)d_in[5];
    const float* b3   = (const float*)d_in[6];
    const float* Wlin = (const float*)d_in[7];
    const float* blin = (const float*)d_in[8];
    const int*   eidx = (const int*)d_in[9];
    const int*   batch= (const int*)d_in[10];
    const int* esrc = eidx;
    const int* edst = eidx + N_EDGES;
    float* out = (float*)d_out;

    char* w = (char*)d_ws;
    size_t off = 0;
    auto alloc = [&](size_t bytes) { size_t o = off; off = (off + bytes + 255) & ~(size_t)255; return o; };
    // cnt and pool adjacent -> one memset zeroes both
    size_t cnt_off = alloc(N_NODES * 4);
    int*   cnt    = (int*)  (w + cnt_off);
    float* pool   = (float*)(w + alloc(NG * 2 * 4));
    size_t zero_bytes = off - cnt_off;
    int*   rowptr = (int*)  (w + alloc((N_NODES + 1) * 4));
    int*   csr    = (int*)  (w + alloc(N_EDGES * 4));
    int*   pos    = (int*)  (w + alloc(N_EDGES * 4));
    float* dinv   = (float*)(w + alloc(N_NODES * 4));
    float* xd     = (float*)(w + alloc(N_NODES * 4));
    float2* s1d   = (float2*)(w + alloc((size_t)N_NODES * 8));
    int*   bsum   = (int*)  (w + alloc(NB_SCAN * 4));
    float* w3buf  = (float*)(w + alloc(260 * 4));
    float* z      = (float*)(w + alloc((size_t)N_NODES * 2 * 4));

    const int FB = (N_EDGES + 255) / 256;   // 2344
    // 1: zero cnt + pool
    hipMemsetAsync(cnt, 0, zero_bytes, stream);
    // 2: degree count + pos + w3lin precompute (extra block)
    k_count<<<EB, 256, 0, stream>>>(edst, cnt, pos, W3, Wlin, b3, blin, w3buf);
    // 3: per-256-chunk sums
    k_blocksum<<<NB_SCAN, 256, 0, stream>>>(cnt, bsum);
    // 4: rowptr + dinv + xd (bsum prefix computed per-block in-kernel)
    k_rowptr<<<NB_SCAN, 256, 0, stream>>>(cnt, bsum, x, rowptr, dinv, xd);
    // 5: CSR fill (atomic-free)
    k_fill<<<FB, 256, 0, stream>>>(esrc, edst, rowptr, pos, csr);
    // 6: layer-1 scalar aggregate (gather, atomic-free)
    k_s1d<<<NB_SCAN, 256, 0, stream>>>(x, xd, dinv, rowptr, csr, s1d);
    // 7: fused reconstruct + GEMM + relu + projection -> z [N,2]
    k_gemm_fused<<<(N_NODES + 63) / 64, 256, 0, stream>>>(s1d, rowptr, csr,
                                                          W1, b1, W2, b2, w3buf, z);
    // 8: layer-3 2-wide aggregation + atomic pool
    k_aggz<<<NB_SCAN, 256, 0, stream>>>(z, rowptr, csr, dinv, batch, pool);
    // 9: mean + consts
    k_final3<<<2, 256, 0, stream>>>(pool, batch, w3buf, out);
}

// Round 10
// 232.956 us; speedup vs baseline: 1.1412x; 1.0083x over previous
//
#include <hip/hip_runtime.h>
#include <hip/hip_bf16.h>

#define N_NODES 50000
#define N_EDGES 600000
#define HID     128
#define NG      500
#define NB_SCAN 196   // ceil(50000/256)
#define EB      2345  // ceil(600000/256) + 1 extra block for w3lin

// ---------------- degree count + pos (+ last block computes w3lin = W3@Wlin) ----------------

__global__ void k_count(const int* __restrict__ dst, int* __restrict__ cnt,
                        int* __restrict__ pos,
                        const float* __restrict__ W3, const float* __restrict__ Wlin,
                        const float* __restrict__ b3, const float* __restrict__ blin,
                        float* __restrict__ w3buf) {
    if (blockIdx.x == EB - 1) {
        int t = threadIdx.x;          // 256 threads -> 128x2
        int k = t >> 1, j = t & 1;
        float acc = 0.f;
        for (int m = 0; m < 128; m++) acc += W3[k * 128 + m] * Wlin[m * 2 + j];
        w3buf[k * 2 + j] = acc;
        if (t < 2) {
            float c = 0.f;
            for (int m = 0; m < 128; m++) c += b3[m] * Wlin[m * 2 + t];
            w3buf[256 + t] = c + blin[t];   // const added to every non-empty graph
            w3buf[258 + t] = blin[t];       // empty-graph fallback
        }
        return;
    }
    int e = blockIdx.x * 256 + threadIdx.x;
    if (e < N_EDGES) pos[e] = atomicAdd(&cnt[dst[e]], 1);
}

__global__ void k_blocksum(const int* __restrict__ cnt, int* __restrict__ bsum) {
    __shared__ int s[256];
    int i = blockIdx.x * 256 + threadIdx.x;
    s[threadIdx.x] = (i < N_NODES) ? cnt[i] : 0;
    __syncthreads();
    for (int o = 128; o; o >>= 1) {
        if (threadIdx.x < o) s[threadIdx.x] += s[threadIdx.x + o];
        __syncthreads();
    }
    if (threadIdx.x == 0) bsum[blockIdx.x] = s[0];
}

// rowptr + dinv + xd; per-block bsum prefix computed in-kernel
__global__ void k_rowptr(const int* __restrict__ cnt, const int* __restrict__ bsum,
                         const float* __restrict__ x,
                         int* __restrict__ rowptr, float* __restrict__ dinv,
                         float* __restrict__ xd) {
    __shared__ int s[256];
    __shared__ int base_sh;
    int v = (threadIdx.x < (int)blockIdx.x && threadIdx.x < NB_SCAN) ? bsum[threadIdx.x] : 0;
    s[threadIdx.x] = v;
    __syncthreads();
    for (int o = 128; o; o >>= 1) {
        if (threadIdx.x < o) s[threadIdx.x] += s[threadIdx.x + o];
        __syncthreads();
    }
    if (threadIdx.x == 0) base_sh = s[0];
    __syncthreads();
    int base = base_sh;
    __syncthreads();

    int i = blockIdx.x * 256 + threadIdx.x;
    int c = (i < N_NODES) ? cnt[i] : 0;
    s[threadIdx.x] = c;
    __syncthreads();
    for (int o = 1; o < 256; o <<= 1) {
        int vv = (threadIdx.x >= o) ? s[threadIdx.x - o] : 0;
        __syncthreads();
        s[threadIdx.x] += vv;
        __syncthreads();
    }
    if (i < N_NODES) {
        int incl = s[threadIdx.x];
        rowptr[i] = base + incl - c;
        float di = rsqrtf((float)c + 1.0f);
        dinv[i] = di;
        xd[i] = x[i] * di;
        if (i == N_NODES - 1) rowptr[N_NODES] = base + incl;
    }
}

// CSR fill — no atomics, independent per edge
__global__ void k_fill(const int* __restrict__ src, const int* __restrict__ dst,
                       const int* __restrict__ rowptr, const int* __restrict__ pos,
                       int* __restrict__ csr) {
    int e = blockIdx.x * 256 + threadIdx.x;
    if (e < N_EDGES) {
        int d = dst[e];
        csr[rowptr[d] + pos[e]] = src[e];
    }
}

// layer-1 scalar aggregate via CSR gather: s1d[i] = {x_i*di^2 + (Σ xd[j])*di, di}
__global__ void k_s1d(const float* __restrict__ x, const float* __restrict__ xd,
                      const float* __restrict__ dinv, const int* __restrict__ rowptr,
                      const int* __restrict__ csr, float2* __restrict__ s1d) {
    int i = blockIdx.x * 256 + threadIdx.x;
    if (i >= N_NODES) return;
    float di = dinv[i];
    int e0 = rowptr[i], e1 = rowptr[i + 1];
    float acc = 0.f;
    int e = e0;
    for (; e + 3 < e1; e += 4)
        acc += xd[csr[e]] + xd[csr[e+1]] + xd[csr[e+2]] + xd[csr[e+3]];
    for (; e < e1; e++) acc += xd[csr[e]];
    float2 r = {x[i] * di * di + acc * di, di};
    s1d[i] = r;
}

// ---------------- Fused: reconstruct-aggregate g=A·h1, GEMM g@W2, relu+b2, ·w3lin -> z[N,2]
// 32-row tile -> 1563 blocks (~6/CU) to fix grid-limited occupancy (R9 lesson).
// Phase A: lane(32) = node, grp(8) = 16-channel chunk; FLOPs unchanged, loads 8x-redundant
// but L1/L2-resident. GEMM: W2 direct from global (L2), one pass over full 128 cols.

__global__ __launch_bounds__(256) void k_gemm_fused(const float2* __restrict__ s1d,
                                                    const int* __restrict__ rowptr,
                                                    const int* __restrict__ csr,
                                                    const float* __restrict__ W1,
                                                    const float* __restrict__ b1,
                                                    const float* __restrict__ W2,
                                                    const float* __restrict__ b2,
                                                    const float* __restrict__ w3buf,
                                                    float* __restrict__ z) {
    __shared__ float HsT[128 * 32];   // 16 KB, [ch][r]
    int t = threadIdx.x;
    int r0 = blockIdx.x * 32;
    int lane = t & 31, grp = t >> 5;  // lane = row in tile, grp = 16-channel chunk (8 x 16)

    float w1r[16], b1r[16];
    #pragma unroll
    for (int kk = 0; kk < 16; kk++) { w1r[kk] = W1[grp * 16 + kk]; b1r[kk] = b1[grp * 16 + kk]; }

    float ga[16];
    #pragma unroll
    for (int kk = 0; kk < 16; kk++) ga[kk] = 0.f;
    int node = r0 + lane;
    if (node < N_NODES) {
        float2 sd = s1d[node];
        float di = sd.y, wself = sd.y * sd.y;
        #pragma unroll
        for (int kk = 0; kk < 16; kk++) ga[kk] = fmaxf(sd.x * w1r[kk] + b1r[kk], 0.f) * wself;
        int e0 = rowptr[node], e1 = rowptr[node + 1];
        int e = e0;
        for (; e + 3 < e1; e += 4) {
            int j0 = csr[e], j1 = csr[e+1], j2 = csr[e+2], j3 = csr[e+3];
            float2 s0 = s1d[j0], s1v = s1d[j1], s2 = s1d[j2], s3 = s1d[j3];
            float wj0 = s0.y * di, wj1 = s1v.y * di, wj2 = s2.y * di, wj3 = s3.y * di;
            #pragma unroll
            for (int kk = 0; kk < 16; kk++) {
                ga[kk] += fmaxf(s0.x  * w1r[kk] + b1r[kk], 0.f) * wj0
                        + fmaxf(s1v.x * w1r[kk] + b1r[kk], 0.f) * wj1
                        + fmaxf(s2.x  * w1r[kk] + b1r[kk], 0.f) * wj2
                        + fmaxf(s3.x  * w1r[kk] + b1r[kk], 0.f) * wj3;
            }
        }
        for (; e < e1; e++) {
            int j0 = csr[e];
            float2 sj0 = s1d[j0];
            float wj0 = sj0.y * di;
            #pragma unroll
            for (int kk = 0; kk < 16; kk++)
                ga[kk] += fmaxf(sj0.x * w1r[kk] + b1r[kk], 0.f) * wj0;
        }
    }
    #pragma unroll
    for (int kk = 0; kk < 16; kk++) HsT[(grp * 16 + kk) * 32 + lane] = ga[kk];
    __syncthreads();

    // GEMM: 32 rows x 128 cols; each thread 4 rows x 4 cols
    int col = (t & 31) * 4;       // 0..124
    int row = (t >> 5) * 4;       // 0..28
    float a[4][4] = {};
    #pragma unroll 4
    for (int k = 0; k < 128; k++) {
        float4 w = *(const float4*)&W2[k * 128 + col];
        float4 h = *(float4*)&HsT[k * 32 + row];
        a[0][0] += h.x * w.x; a[0][1] += h.x * w.y; a[0][2] += h.x * w.z; a[0][3] += h.x * w.w;
        a[1][0] += h.y * w.x; a[1][1] += h.y * w.y; a[1][2] += h.y * w.z; a[1][3] += h.y * w.w;
        a[2][0] += h.z * w.x; a[2][1] += h.z * w.y; a[2][2] += h.z * w.z; a[2][3] += h.z * w.w;
        a[3][0] += h.w * w.x; a[3][1] += h.w * w.y; a[3][2] += h.w * w.z; a[3][3] += h.w * w.w;
    }

    // epilogue: relu(+b2), project to 2 outputs, reduce across the 32 lanes of a row group
    float b2r[4], w0r[4], w1rr[4];
    #pragma unroll
    for (int c = 0; c < 4; c++) {
        b2r[c] = b2[col + c];
        w0r[c] = w3buf[(col + c) * 2 + 0];
        w1rr[c] = w3buf[(col + c) * 2 + 1];
    }
    #pragma unroll
    for (int r = 0; r < 4; r++) {
        float p0 = 0.f, p1 = 0.f;
        #pragma unroll
        for (int c = 0; c < 4; c++) {
            float v0 = fmaxf(a[r][c] + b2r[c], 0.f);
            p0 += v0 * w0r[c];
            p1 += v0 * w1rr[c];
        }
        for (int o = 1; o < 32; o <<= 1) { p0 += __shfl_xor(p0, o); p1 += __shfl_xor(p1, o); }
        int rg = r0 + row + r;
        if ((t & 31) == 0 && rg < N_NODES) { z[rg * 2 + 0] = p0; z[rg * 2 + 1] = p1; }
    }
}

// ---------------- Layer-3 aggregation on z (2-wide) + atomic pool ----------------

__global__ void k_aggz(const float* __restrict__ z, const int* __restrict__ rowptr,
                       const int* __restrict__ csr, const float* __restrict__ dinv,
                       const int* __restrict__ batch, float* __restrict__ pool) {
    int i = blockIdx.x * 256 + threadIdx.x;
    if (i >= N_NODES) return;
    const float2* Z = (const float2*)z;
    float di = dinv[i];
    float2 zi = Z[i];
    float a0 = zi.x * di * di, a1 = zi.y * di * di;
    int e0 = rowptr[i], e1 = rowptr[i + 1];
    int e = e0;
    for (; e + 3 < e1; e += 4) {
        int s0 = csr[e], s1 = csr[e+1], s2 = csr[e+2], s3 = csr[e+3];
        float w0 = dinv[s0]*di, w1 = dinv[s1]*di, w2 = dinv[s2]*di, w3 = dinv[s3]*di;
        float2 za = Z[s0], zb = Z[s1], zc = Z[s2], zd = Z[s3];
        a0 += za.x*w0 + zb.x*w1 + zc.x*w2 + zd.x*w3;
        a1 += za.y*w0 + zb.y*w1 + zc.y*w2 + zd.y*w3;
    }
    for (; e < e1; e++) {
        int s = csr[e];
        float w = dinv[s] * di;
        float2 za = Z[s];
        a0 += za.x * w; a1 += za.y * w;
    }
    int g = batch[i];
    atomicAdd(&pool[g * 2 + 0], a0);
    atomicAdd(&pool[g * 2 + 1], a1);
}

// ---------------- Final: mean + consts (batch sorted; counts via binary search) ----------------

__global__ __launch_bounds__(256) void k_final3(const float* __restrict__ pool,
                                                const int* __restrict__ batch,
                                                const float* __restrict__ w3buf,
                                                float* __restrict__ out) {
    int g = blockIdx.x * 256 + threadIdx.x;
    if (g >= NG) return;
    int lo = 0, hi = N_NODES;
    while (lo < hi) { int mid = (lo + hi) >> 1; if (batch[mid] < g) lo = mid + 1; else hi = mid; }
    int start = lo;
    hi = N_NODES;
    while (lo < hi) { int mid = (lo + hi) >> 1; if (batch[mid] < g + 1) lo = mid + 1; else hi = mid; }
    int end = lo;
    if (end > start) {
        float inv = 1.0f / (float)(end - start);
        out[g * 2 + 0] = pool[g * 2 + 0] * inv + w3buf[256];
        out[g * 2 + 1] = pool[g * 2 + 1] * inv + w3buf[257];
    } else {
        out[g * 2 + 0] = w3buf[258];
        out[g * 2 + 1] = w3buf[259];
    }
}

// ---------------- launch ----------------

extern "C" void kernel_launch(void* const* d_in, const int* in_sizes, int n_in,
                              void* d_out, int out_size, void* d_ws, size_t ws_size,
                              hipStream_t stream) {
    const float* x    = (const float*)d_in[0];
    const float* W1   = (const float*)d_in[1];
    const float* b1   = (const float*)d_in[2];
    const float* W2   = (const float*)d_in[3];
    const float* b2   = (const float*)d_in[4];
    const float* W3   = (const float*)d_in[5];
    const float* b3   = (const float*)d_in[6];
    const float* Wlin = (const float*)d_in[7];
    const float* blin = (const float*)d_in[8];
    const int*   eidx = (const int*)d_in[9];
    const int*   batch= (const int*)d_in[10];
    const int* esrc = eidx;
    const int* edst = eidx + N_EDGES;
    float* out = (float*)d_out;

    char* w = (char*)d_ws;
    size_t off = 0;
    auto alloc = [&](size_t bytes) { size_t o = off; off = (off + bytes + 255) & ~(size_t)255; return o; };
    // cnt and pool adjacent -> one memset zeroes both
    size_t cnt_off = alloc(N_NODES * 4);
    int*   cnt    = (int*)  (w + cnt_off);
    float* pool   = (float*)(w + alloc(NG * 2 * 4));
    size_t zero_bytes = off - cnt_off;
    int*   rowptr = (int*)  (w + alloc((N_NODES + 1) * 4));
    int*   csr    = (int*)  (w + alloc(N_EDGES * 4));
    int*   pos    = (int*)  (w + alloc(N_EDGES * 4));
    float* dinv   = (float*)(w + alloc(N_NODES * 4));
    float* xd     = (float*)(w + alloc(N_NODES * 4));
    float2* s1d   = (float2*)(w + alloc((size_t)N_NODES * 8));
    int*   bsum   = (int*)  (w + alloc(NB_SCAN * 4));
    float* w3buf  = (float*)(w + alloc(260 * 4));
    float* z      = (float*)(w + alloc((size_t)N_NODES * 2 * 4));

    const int FB = (N_EDGES + 255) / 256;   // 2344
    // 1: zero cnt + pool
    hipMemsetAsync(cnt, 0, zero_bytes, stream);
    // 2: degree count + pos + w3lin precompute (extra block)
    k_count<<<EB, 256, 0, stream>>>(edst, cnt, pos, W3, Wlin, b3, blin, w3buf);
    // 3: per-256-chunk sums
    k_blocksum<<<NB_SCAN, 256, 0, stream>>>(cnt, bsum);
    // 4: rowptr + dinv + xd
    k_rowptr<<<NB_SCAN, 256, 0, stream>>>(cnt, bsum, x, rowptr, dinv, xd);
    // 5: CSR fill (atomic-free)
    k_fill<<<FB, 256, 0, stream>>>(esrc, edst, rowptr, pos, csr);
    // 6: layer-1 scalar aggregate (gather, atomic-free)
    k_s1d<<<NB_SCAN, 256, 0, stream>>>(x, xd, dinv, rowptr, csr, s1d);
    // 7: fused reconstruct + GEMM + relu + projection -> z [N,2]  (32-row tiles)
    k_gemm_fused<<<(N_NODES + 31) / 32, 256, 0, stream>>>(s1d, rowptr, csr,
                                                          W1, b1, W2, b2, w3buf, z);
    // 8: layer-3 2-wide aggregation + atomic pool
    k_aggz<<<NB_SCAN, 256, 0, stream>>>(z, rowptr, csr, dinv, batch, pool);
    // 9: mean + consts
    k_final3<<<2, 256, 0, stream>>>(pool, batch, w3buf, out);
}

// Round 11
// 232.288 us; speedup vs baseline: 1.1445x; 1.0029x over previous
//
#include <hip/hip_runtime.h>
#include <hip/hip_bf16.h>

#define N_NODES 50000
#define N_EDGES 600000
#define HID     128
#define NG      500
#define NB_SCAN 196   // ceil(50000/256)
#define EB      2345  // ceil(600000/256) + 1 extra block for w3lin
#define ECAP    768   // LDS edge-slice capacity (mean 384, sd 62 -> +6 sigma)

// ---------------- degree count + pos (+ last block computes w3lin = W3@Wlin) ----------------

__global__ void k_count(const int* __restrict__ dst, int* __restrict__ cnt,
                        int* __restrict__ pos,
                        const float* __restrict__ W3, const float* __restrict__ Wlin,
                        const float* __restrict__ b3, const float* __restrict__ blin,
                        float* __restrict__ w3buf) {
    if (blockIdx.x == EB - 1) {
        int t = threadIdx.x;          // 256 threads -> 128x2
        int k = t >> 1, j = t & 1;
        float acc = 0.f;
        for (int m = 0; m < 128; m++) acc += W3[k * 128 + m] * Wlin[m * 2 + j];
        w3buf[k * 2 + j] = acc;
        if (t < 2) {
            float c = 0.f;
            for (int m = 0; m < 128; m++) c += b3[m] * Wlin[m * 2 + t];
            w3buf[256 + t] = c + blin[t];   // const added to every non-empty graph
            w3buf[258 + t] = blin[t];       // empty-graph fallback
        }
        return;
    }
    int e = blockIdx.x * 256 + threadIdx.x;
    if (e < N_EDGES) pos[e] = atomicAdd(&cnt[dst[e]], 1);
}

__global__ void k_blocksum(const int* __restrict__ cnt, int* __restrict__ bsum) {
    __shared__ int s[256];
    int i = blockIdx.x * 256 + threadIdx.x;
    s[threadIdx.x] = (i < N_NODES) ? cnt[i] : 0;
    __syncthreads();
    for (int o = 128; o; o >>= 1) {
        if (threadIdx.x < o) s[threadIdx.x] += s[threadIdx.x + o];
        __syncthreads();
    }
    if (threadIdx.x == 0) bsum[blockIdx.x] = s[0];
}

// rowptr + dinv + xd; per-block bsum prefix computed in-kernel
__global__ void k_rowptr(const int* __restrict__ cnt, const int* __restrict__ bsum,
                         const float* __restrict__ x,
                         int* __restrict__ rowptr, float* __restrict__ dinv,
                         float* __restrict__ xd) {
    __shared__ int s[256];
    __shared__ int base_sh;
    int v = (threadIdx.x < (int)blockIdx.x && threadIdx.x < NB_SCAN) ? bsum[threadIdx.x] : 0;
    s[threadIdx.x] = v;
    __syncthreads();
    for (int o = 128; o; o >>= 1) {
        if (threadIdx.x < o) s[threadIdx.x] += s[threadIdx.x + o];
        __syncthreads();
    }
    if (threadIdx.x == 0) base_sh = s[0];
    __syncthreads();
    int base = base_sh;
    __syncthreads();

    int i = blockIdx.x * 256 + threadIdx.x;
    int c = (i < N_NODES) ? cnt[i] : 0;
    s[threadIdx.x] = c;
    __syncthreads();
    for (int o = 1; o < 256; o <<= 1) {
        int vv = (threadIdx.x >= o) ? s[threadIdx.x - o] : 0;
        __syncthreads();
        s[threadIdx.x] += vv;
        __syncthreads();
    }
    if (i < N_NODES) {
        int incl = s[threadIdx.x];
        rowptr[i] = base + incl - c;
        float di = rsqrtf((float)c + 1.0f);
        dinv[i] = di;
        xd[i] = x[i] * di;
        if (i == N_NODES - 1) rowptr[N_NODES] = base + incl;
    }
}

// CSR fill — no atomics, independent per edge
__global__ void k_fill(const int* __restrict__ src, const int* __restrict__ dst,
                       const int* __restrict__ rowptr, const int* __restrict__ pos,
                       int* __restrict__ csr) {
    int e = blockIdx.x * 256 + threadIdx.x;
    if (e < N_EDGES) {
        int d = dst[e];
        csr[rowptr[d] + pos[e]] = src[e];
    }
}

// layer-1 scalar aggregate via CSR gather: s1d[i] = {x_i*di^2 + (Σ xd[j])*di, di}
__global__ void k_s1d(const float* __restrict__ x, const float* __restrict__ xd,
                      const float* __restrict__ dinv, const int* __restrict__ rowptr,
                      const int* __restrict__ csr, float2* __restrict__ s1d) {
    int i = blockIdx.x * 256 + threadIdx.x;
    if (i >= N_NODES) return;
    float di = dinv[i];
    int e0 = rowptr[i], e1 = rowptr[i + 1];
    float acc = 0.f;
    int e = e0;
    for (; e + 3 < e1; e += 4)
        acc += xd[csr[e]] + xd[csr[e+1]] + xd[csr[e+2]] + xd[csr[e+3]];
    for (; e < e1; e++) acc += xd[csr[e]];
    float2 r = {x[i] * di * di + acc * di, di};
    s1d[i] = r;
}

// ---------------- Fused: reconstruct-aggregate g=A·h1, GEMM g@W2, relu+b2, ·w3lin -> z[N,2]
// 32-row tile. Phase A dedup (R10 lesson): the block's CSR slice is CONTIGUOUS
// [rowptr[r0], rowptr[r0+32]) — stage csr + s1d[j] into LDS once (600k gathers total
// instead of 8x-redundant 4.8M), then per-lane walks read LDS. GEMM: W2 from global (L2).

__global__ __launch_bounds__(256) void k_gemm_fused(const float2* __restrict__ s1d,
                                                    const int* __restrict__ rowptr,
                                                    const int* __restrict__ csr,
                                                    const float* __restrict__ W1,
                                                    const float* __restrict__ b1,
                                                    const float* __restrict__ W2,
                                                    const float* __restrict__ b2,
                                                    const float* __restrict__ w3buf,
                                                    float* __restrict__ z) {
    __shared__ float HsT[128 * 32];   // 16 KB, [ch][r]
    __shared__ int rp_sh[33];
    __shared__ int csr_sh[ECAP];      // 3 KB
    __shared__ float2 sjd_sh[ECAP];   // 6 KB
    int t = threadIdx.x;
    int r0 = blockIdx.x * 32;
    int lane = t & 31, grp = t >> 5;  // lane = row in tile, grp = 16-channel chunk (8 x 16)

    if (t < 33) {
        int i = r0 + t;
        rp_sh[t] = rowptr[(i <= N_NODES) ? i : N_NODES];
    }
    __syncthreads();
    int estart = rp_sh[0];
    int len = rp_sh[32] - estart;
    bool fast = (len <= ECAP);
    if (fast) {
        for (int i = t; i < len; i += 256) csr_sh[i] = csr[estart + i];
        __syncthreads();
        for (int i = t; i < len; i += 256) sjd_sh[i] = s1d[csr_sh[i]];
    }
    __syncthreads();

    float w1r[16], b1r[16];
    #pragma unroll
    for (int kk = 0; kk < 16; kk++) { w1r[kk] = W1[grp * 16 + kk]; b1r[kk] = b1[grp * 16 + kk]; }

    float ga[16];
    #pragma unroll
    for (int kk = 0; kk < 16; kk++) ga[kk] = 0.f;
    int node = r0 + lane;
    if (node < N_NODES) {
        float2 sd = s1d[node];
        float di = sd.y, wself = sd.y * sd.y;
        #pragma unroll
        for (int kk = 0; kk < 16; kk++) ga[kk] = fmaxf(sd.x * w1r[kk] + b1r[kk], 0.f) * wself;
        int e0 = rp_sh[lane] - estart, e1 = rp_sh[lane + 1] - estart;
        if (fast) {
            int e = e0;
            for (; e + 3 < e1; e += 4) {
                float2 s0 = sjd_sh[e], s1v = sjd_sh[e+1], s2 = sjd_sh[e+2], s3 = sjd_sh[e+3];
                float wj0 = s0.y * di, wj1 = s1v.y * di, wj2 = s2.y * di, wj3 = s3.y * di;
                #pragma unroll
                for (int kk = 0; kk < 16; kk++) {
                    ga[kk] += fmaxf(s0.x  * w1r[kk] + b1r[kk], 0.f) * wj0
                            + fmaxf(s1v.x * w1r[kk] + b1r[kk], 0.f) * wj1
                            + fmaxf(s2.x  * w1r[kk] + b1r[kk], 0.f) * wj2
                            + fmaxf(s3.x  * w1r[kk] + b1r[kk], 0.f) * wj3;
                }
            }
            for (; e < e1; e++) {
                float2 sj = sjd_sh[e];
                float wj = sj.y * di;
                #pragma unroll
                for (int kk = 0; kk < 16; kk++)
                    ga[kk] += fmaxf(sj.x * w1r[kk] + b1r[kk], 0.f) * wj;
            }
        } else {   // overflow fallback (block-uniform, ~never taken)
            for (int e = e0; e < e1; e++) {
                float2 sj = s1d[csr[estart + e]];
                float wj = sj.y * di;
                #pragma unroll
                for (int kk = 0; kk < 16; kk++)
                    ga[kk] += fmaxf(sj.x * w1r[kk] + b1r[kk], 0.f) * wj;
            }
        }
    }
    #pragma unroll
    for (int kk = 0; kk < 16; kk++) HsT[(grp * 16 + kk) * 32 + lane] = ga[kk];
    __syncthreads();

    // GEMM: 32 rows x 128 cols; each thread 4 rows x 4 cols
    int col = (t & 31) * 4;       // 0..124
    int row = (t >> 5) * 4;       // 0..28
    float a[4][4] = {};
    #pragma unroll 4
    for (int k = 0; k < 128; k++) {
        float4 w = *(const float4*)&W2[k * 128 + col];
        float4 h = *(float4*)&HsT[k * 32 + row];
        a[0][0] += h.x * w.x; a[0][1] += h.x * w.y; a[0][2] += h.x * w.z; a[0][3] += h.x * w.w;
        a[1][0] += h.y * w.x; a[1][1] += h.y * w.y; a[1][2] += h.y * w.z; a[1][3] += h.y * w.w;
        a[2][0] += h.z * w.x; a[2][1] += h.z * w.y; a[2][2] += h.z * w.z; a[2][3] += h.z * w.w;
        a[3][0] += h.w * w.x; a[3][1] += h.w * w.y; a[3][2] += h.w * w.z; a[3][3] += h.w * w.w;
    }

    // epilogue: relu(+b2), project to 2 outputs, reduce across the 32 lanes of a row group
    float b2r[4], w0r[4], w1rr[4];
    #pragma unroll
    for (int c = 0; c < 4; c++) {
        b2r[c] = b2[col + c];
        w0r[c] = w3buf[(col + c) * 2 + 0];
        w1rr[c] = w3buf[(col + c) * 2 + 1];
    }
    #pragma unroll
    for (int r = 0; r < 4; r++) {
        float p0 = 0.f, p1 = 0.f;
        #pragma unroll
        for (int c = 0; c < 4; c++) {
            float v0 = fmaxf(a[r][c] + b2r[c], 0.f);
            p0 += v0 * w0r[c];
            p1 += v0 * w1rr[c];
        }
        for (int o = 1; o < 32; o <<= 1) { p0 += __shfl_xor(p0, o); p1 += __shfl_xor(p1, o); }
        int rg = r0 + row + r;
        if ((t & 31) == 0 && rg < N_NODES) { z[rg * 2 + 0] = p0; z[rg * 2 + 1] = p1; }
    }
}

// ---------------- Layer-3 aggregation on z (2-wide) + atomic pool ----------------

__global__ void k_aggz(const float* __restrict__ z, const int* __restrict__ rowptr,
                       const int* __restrict__ csr, const float* __restrict__ dinv,
                       const int* __restrict__ batch, float* __restrict__ pool) {
    int i = blockIdx.x * 256 + threadIdx.x;
    if (i >= N_NODES) return;
    const float2* Z = (const float2*)z;
    float di = dinv[i];
    float2 zi = Z[i];
    float a0 = zi.x * di * di, a1 = zi.y * di * di;
    int e0 = rowptr[i], e1 = rowptr[i + 1];
    int e = e0;
    for (; e + 3 < e1; e += 4) {
        int s0 = csr[e], s1 = csr[e+1], s2 = csr[e+2], s3 = csr[e+3];
        float w0 = dinv[s0]*di, w1 = dinv[s1]*di, w2 = dinv[s2]*di, w3 = dinv[s3]*di;
        float2 za = Z[s0], zb = Z[s1], zc = Z[s2], zd = Z[s3];
        a0 += za.x*w0 + zb.x*w1 + zc.x*w2 + zd.x*w3;
        a1 += za.y*w0 + zb.y*w1 + zc.y*w2 + zd.y*w3;
    }
    for (; e < e1; e++) {
        int s = csr[e];
        float w = dinv[s] * di;
        float2 za = Z[s];
        a0 += za.x * w; a1 += za.y * w;
    }
    int g = batch[i];
    atomicAdd(&pool[g * 2 + 0], a0);
    atomicAdd(&pool[g * 2 + 1], a1);
}

// ---------------- Final: mean + consts (batch sorted; counts via binary search) ----------------

__global__ __launch_bounds__(256) void k_final3(const float* __restrict__ pool,
                                                const int* __restrict__ batch,
                                                const float* __restrict__ w3buf,
                                                float* __restrict__ out) {
    int g = blockIdx.x * 256 + threadIdx.x;
    if (g >= NG) return;
    int lo = 0, hi = N_NODES;
    while (lo < hi) { int mid = (lo + hi) >> 1; if (batch[mid] < g) lo = mid + 1; else hi = mid; }
    int start = lo;
    hi = N_NODES;
    while (lo < hi) { int mid = (lo + hi) >> 1; if (batch[mid] < g + 1) lo = mid + 1; else hi = mid; }
    int end = lo;
    if (end > start) {
        float inv = 1.0f / (float)(end - start);
        out[g * 2 + 0] = pool[g * 2 + 0] * inv + w3buf[256];
        out[g * 2 + 1] = pool[g * 2 + 1] * inv + w3buf[257];
    } else {
        out[g * 2 + 0] = w3buf[258];
        out[g * 2 + 1] = w3buf[259];
    }
}

// ---------------- launch ----------------

extern "C" void kernel_launch(void* const* d_in, const int* in_sizes, int n_in,
                              void* d_out, int out_size, void* d_ws, size_t ws_size,
                              hipStream_t stream) {
    const float* x    = (const float*)d_in[0];
    const float* W1   = (const float*)d_in[1];
    const float* b1   = (const float*)d_in[2];
    const float* W2   = (const float*)d_in[3];
    const float* b2   = (const float*)d_in[4];
    const float* W3   = (const float*)d_in[5];
    const float* b3   = (const float*)d_in[6];
    const float* Wlin = (const float*)d_in[7];
    const float* blin = (const float*)d_in[8];
    const int*   eidx = (const int*)d_in[9];
    const int*   batch= (const int*)d_in[10];
    const int* esrc = eidx;
    const int* edst = eidx + N_EDGES;
    float* out = (float*)d_out;

    char* w = (char*)d_ws;
    size_t off = 0;
    auto alloc = [&](size_t bytes) { size_t o = off; off = (off + bytes + 255) & ~(size_t)255; return o; };
    // cnt and pool adjacent -> one memset zeroes both
    size_t cnt_off = alloc(N_NODES * 4);
    int*   cnt    = (int*)  (w + cnt_off);
    float* pool   = (float*)(w + alloc(NG * 2 * 4));
    size_t zero_bytes = off - cnt_off;
    int*   rowptr = (int*)  (w + alloc((N_NODES + 1) * 4));
    int*   csr    = (int*)  (w + alloc(N_EDGES * 4));
    int*   pos    = (int*)  (w + alloc(N_EDGES * 4));
    float* dinv   = (float*)(w + alloc(N_NODES * 4));
    float* xd     = (float*)(w + alloc(N_NODES * 4));
    float2* s1d   = (float2*)(w + alloc((size_t)N_NODES * 8));
    int*   bsum   = (int*)  (w + alloc(NB_SCAN * 4));
    float* w3buf  = (float*)(w + alloc(260 * 4));
    float* z      = (float*)(w + alloc((size_t)N_NODES * 2 * 4));

    const int FB = (N_EDGES + 255) / 256;   // 2344
    // 1: zero cnt + pool
    hipMemsetAsync(cnt, 0, zero_bytes, stream);
    // 2: degree count + pos + w3lin precompute (extra block)
    k_count<<<EB, 256, 0, stream>>>(edst, cnt, pos, W3, Wlin, b3, blin, w3buf);
    // 3: per-256-chunk sums
    k_blocksum<<<NB_SCAN, 256, 0, stream>>>(cnt, bsum);
    // 4: rowptr + dinv + xd
    k_rowptr<<<NB_SCAN, 256, 0, stream>>>(cnt, bsum, x, rowptr, dinv, xd);
    // 5: CSR fill (atomic-free)
    k_fill<<<FB, 256, 0, stream>>>(esrc, edst, rowptr, pos, csr);
    // 6: layer-1 scalar aggregate (gather, atomic-free)
    k_s1d<<<NB_SCAN, 256, 0, stream>>>(x, xd, dinv, rowptr, csr, s1d);
    // 7: fused reconstruct + GEMM + relu + projection -> z [N,2]  (32-row tiles, LDS dedup)
    k_gemm_fused<<<(N_NODES + 31) / 32, 256, 0, stream>>>(s1d, rowptr, csr,
                                                          W1, b1, W2, b2, w3buf, z);
    // 8: layer-3 2-wide aggregation + atomic pool
    k_aggz<<<NB_SCAN, 256, 0, stream>>>(z, rowptr, csr, dinv, batch, pool);
    // 9: mean + consts
    k_final3<<<2, 256, 0, stream>>>(pool, batch, w3buf, out);
}

// Round 12
// 224.247 us; speedup vs baseline: 1.1855x; 1.0359x over previous
//
#include <hip/hip_runtime.h>
#include <hip/hip_bf16.h>

#define N_NODES 50000
#define N_EDGES 600000
#define HID     128
#define NG      500
#define NB_SCAN 196   // ceil(50000/256)
#define EB      2345  // ceil(600000/256) + 1 extra block for w3lin
#define ECAP    768   // LDS edge-slice capacity (mean 384, sd 62 -> +6 sigma)

// ---------------- degree count + pos (+ last block computes w3lin = W3@Wlin) ----------------

__global__ void k_count(const int* __restrict__ dst, int* __restrict__ cnt,
                        int* __restrict__ pos,
                        const float* __restrict__ W3, const float* __restrict__ Wlin,
                        const float* __restrict__ b3, const float* __restrict__ blin,
                        float* __restrict__ w3buf) {
    if (blockIdx.x == EB - 1) {
        int t = threadIdx.x;          // 256 threads -> 128x2
        int k = t >> 1, j = t & 1;
        float acc = 0.f;
        for (int m = 0; m < 128; m++) acc += W3[k * 128 + m] * Wlin[m * 2 + j];
        w3buf[k * 2 + j] = acc;
        if (t < 2) {
            float c = 0.f;
            for (int m = 0; m < 128; m++) c += b3[m] * Wlin[m * 2 + t];
            w3buf[256 + t] = c + blin[t];   // const added to every non-empty graph
            w3buf[258 + t] = blin[t];       // empty-graph fallback
        }
        return;
    }
    int e = blockIdx.x * 256 + threadIdx.x;
    if (e < N_EDGES) pos[e] = atomicAdd(&cnt[dst[e]], 1);
}

__global__ void k_blocksum(const int* __restrict__ cnt, int* __restrict__ bsum) {
    __shared__ int s[256];
    int i = blockIdx.x * 256 + threadIdx.x;
    s[threadIdx.x] = (i < N_NODES) ? cnt[i] : 0;
    __syncthreads();
    for (int o = 128; o; o >>= 1) {
        if (threadIdx.x < o) s[threadIdx.x] += s[threadIdx.x + o];
        __syncthreads();
    }
    if (threadIdx.x == 0) bsum[blockIdx.x] = s[0];
}

// rowptr + dinv + xd; per-block bsum prefix computed in-kernel
__global__ void k_rowptr(const int* __restrict__ cnt, const int* __restrict__ bsum,
                         const float* __restrict__ x,
                         int* __restrict__ rowptr, float* __restrict__ dinv,
                         float* __restrict__ xd) {
    __shared__ int s[256];
    __shared__ int base_sh;
    int v = (threadIdx.x < (int)blockIdx.x && threadIdx.x < NB_SCAN) ? bsum[threadIdx.x] : 0;
    s[threadIdx.x] = v;
    __syncthreads();
    for (int o = 128; o; o >>= 1) {
        if (threadIdx.x < o) s[threadIdx.x] += s[threadIdx.x + o];
        __syncthreads();
    }
    if (threadIdx.x == 0) base_sh = s[0];
    __syncthreads();
    int base = base_sh;
    __syncthreads();

    int i = blockIdx.x * 256 + threadIdx.x;
    int c = (i < N_NODES) ? cnt[i] : 0;
    s[threadIdx.x] = c;
    __syncthreads();
    for (int o = 1; o < 256; o <<= 1) {
        int vv = (threadIdx.x >= o) ? s[threadIdx.x - o] : 0;
        __syncthreads();
        s[threadIdx.x] += vv;
        __syncthreads();
    }
    if (i < N_NODES) {
        int incl = s[threadIdx.x];
        rowptr[i] = base + incl - c;
        float di = rsqrtf((float)c + 1.0f);
        dinv[i] = di;
        xd[i] = x[i] * di;
        if (i == N_NODES - 1) rowptr[N_NODES] = base + incl;
    }
}

// CSR fill — no atomics, independent per edge
__global__ void k_fill(const int* __restrict__ src, const int* __restrict__ dst,
                       const int* __restrict__ rowptr, const int* __restrict__ pos,
                       int* __restrict__ csr) {
    int e = blockIdx.x * 256 + threadIdx.x;
    if (e < N_EDGES) {
        int d = dst[e];
        csr[rowptr[d] + pos[e]] = src[e];
    }
}

// layer-1 scalar aggregate, 4 lanes per node (TLP fix, R11 lesson):
// s1d[i] = {x_i*di^2 + (Σ xd[j])*di, di}
__global__ void k_s1d(const float* __restrict__ x, const float* __restrict__ xd,
                      const float* __restrict__ dinv, const int* __restrict__ rowptr,
                      const int* __restrict__ csr, float2* __restrict__ s1d) {
    int tid = blockIdx.x * 256 + threadIdx.x;
    int i = tid >> 2, sub = tid & 3;
    if (i >= N_NODES) return;
    int e0 = rowptr[i], e1 = rowptr[i + 1];
    float acc = 0.f;
    for (int e = e0 + sub; e < e1; e += 4) acc += xd[csr[e]];
    acc += __shfl_xor(acc, 1);
    acc += __shfl_xor(acc, 2);
    if (sub == 0) {
        float di = dinv[i];
        float2 r = {x[i] * di * di + acc * di, di};
        s1d[i] = r;
    }
}

// ---------------- Fused: reconstruct-aggregate g=A·h1, GEMM g@W2, relu+b2, ·w3lin -> zd[N,2]
// 32-row tile; CSR slice + s1d gathered once into LDS (R11-proven). Epilogue stores
// zd_i = z_i * dinv_i so the layer-3 pass needs only ONE gather per edge.

__global__ __launch_bounds__(256) void k_gemm_fused(const float2* __restrict__ s1d,
                                                    const int* __restrict__ rowptr,
                                                    const int* __restrict__ csr,
                                                    const float* __restrict__ W1,
                                                    const float* __restrict__ b1,
                                                    const float* __restrict__ W2,
                                                    const float* __restrict__ b2,
                                                    const float* __restrict__ w3buf,
                                                    float* __restrict__ zd) {
    __shared__ float HsT[128 * 32];   // 16 KB, [ch][r]
    __shared__ int rp_sh[33];
    __shared__ int csr_sh[ECAP];      // 3 KB
    __shared__ float2 sjd_sh[ECAP];   // 6 KB
    int t = threadIdx.x;
    int r0 = blockIdx.x * 32;
    int lane = t & 31, grp = t >> 5;  // lane = row in tile, grp = 16-channel chunk (8 x 16)

    if (t < 33) {
        int i = r0 + t;
        rp_sh[t] = rowptr[(i <= N_NODES) ? i : N_NODES];
    }
    __syncthreads();
    int estart = rp_sh[0];
    int len = rp_sh[32] - estart;
    bool fast = (len <= ECAP);
    if (fast) {
        for (int i = t; i < len; i += 256) csr_sh[i] = csr[estart + i];
        __syncthreads();
        for (int i = t; i < len; i += 256) sjd_sh[i] = s1d[csr_sh[i]];
    }
    __syncthreads();

    float w1r[16], b1r[16];
    #pragma unroll
    for (int kk = 0; kk < 16; kk++) { w1r[kk] = W1[grp * 16 + kk]; b1r[kk] = b1[grp * 16 + kk]; }

    float ga[16];
    #pragma unroll
    for (int kk = 0; kk < 16; kk++) ga[kk] = 0.f;
    int node = r0 + lane;
    float di_self = 0.f;
    if (node < N_NODES) {
        float2 sd = s1d[node];
        di_self = sd.y;
        float di = sd.y, wself = sd.y * sd.y;
        #pragma unroll
        for (int kk = 0; kk < 16; kk++) ga[kk] = fmaxf(sd.x * w1r[kk] + b1r[kk], 0.f) * wself;
        int e0 = rp_sh[lane] - estart, e1 = rp_sh[lane + 1] - estart;
        if (fast) {
            int e = e0;
            for (; e + 3 < e1; e += 4) {
                float2 s0 = sjd_sh[e], s1v = sjd_sh[e+1], s2 = sjd_sh[e+2], s3 = sjd_sh[e+3];
                float wj0 = s0.y * di, wj1 = s1v.y * di, wj2 = s2.y * di, wj3 = s3.y * di;
                #pragma unroll
                for (int kk = 0; kk < 16; kk++) {
                    ga[kk] += fmaxf(s0.x  * w1r[kk] + b1r[kk], 0.f) * wj0
                            + fmaxf(s1v.x * w1r[kk] + b1r[kk], 0.f) * wj1
                            + fmaxf(s2.x  * w1r[kk] + b1r[kk], 0.f) * wj2
                            + fmaxf(s3.x  * w1r[kk] + b1r[kk], 0.f) * wj3;
                }
            }
            for (; e < e1; e++) {
                float2 sj = sjd_sh[e];
                float wj = sj.y * di;
                #pragma unroll
                for (int kk = 0; kk < 16; kk++)
                    ga[kk] += fmaxf(sj.x * w1r[kk] + b1r[kk], 0.f) * wj;
            }
        } else {   // overflow fallback (block-uniform, ~never taken)
            for (int e = e0; e < e1; e++) {
                float2 sj = s1d[csr[estart + e]];
                float wj = sj.y * di;
                #pragma unroll
                for (int kk = 0; kk < 16; kk++)
                    ga[kk] += fmaxf(sj.x * w1r[kk] + b1r[kk], 0.f) * wj;
            }
        }
    }
    #pragma unroll
    for (int kk = 0; kk < 16; kk++) HsT[(grp * 16 + kk) * 32 + lane] = ga[kk];
    __syncthreads();

    // GEMM: 32 rows x 128 cols; each thread 4 rows x 4 cols
    int col = (t & 31) * 4;       // 0..124
    int row = (t >> 5) * 4;       // 0..28
    float a[4][4] = {};
    #pragma unroll 4
    for (int k = 0; k < 128; k++) {
        float4 w = *(const float4*)&W2[k * 128 + col];
        float4 h = *(float4*)&HsT[k * 32 + row];
        a[0][0] += h.x * w.x; a[0][1] += h.x * w.y; a[0][2] += h.x * w.z; a[0][3] += h.x * w.w;
        a[1][0] += h.y * w.x; a[1][1] += h.y * w.y; a[1][2] += h.y * w.z; a[1][3] += h.y * w.w;
        a[2][0] += h.z * w.x; a[2][1] += h.z * w.y; a[2][2] += h.z * w.z; a[2][3] += h.z * w.w;
        a[3][0] += h.w * w.x; a[3][1] += h.w * w.y; a[3][2] += h.w * w.z; a[3][3] += h.w * w.w;
    }

    // epilogue: relu(+b2), project to 2 outputs, scale by dinv (zd = z*di), store
    float b2r[4], w0r[4], w1rr[4];
    #pragma unroll
    for (int c = 0; c < 4; c++) {
        b2r[c] = b2[col + c];
        w0r[c] = w3buf[(col + c) * 2 + 0];
        w1rr[c] = w3buf[(col + c) * 2 + 1];
    }
    #pragma unroll
    for (int r = 0; r < 4; r++) {
        float p0 = 0.f, p1 = 0.f;
        #pragma unroll
        for (int c = 0; c < 4; c++) {
            float v0 = fmaxf(a[r][c] + b2r[c], 0.f);
            p0 += v0 * w0r[c];
            p1 += v0 * w1rr[c];
        }
        for (int o = 1; o < 32; o <<= 1) { p0 += __shfl_xor(p0, o); p1 += __shfl_xor(p1, o); }
        int rg = r0 + row + r;
        if ((t & 31) == 0 && rg < N_NODES) {
            float dr = __shfl(di_self, row + r, 64);   // dinv of row rg lives in lane row+r
            // NOTE: di_self is per-lane of grp 0..7; lane (row+r) of THIS wave's first 32 lanes
            // holds node r0+row+r only when grp==0. Safer: reload.
            dr = s1d[rg].y;
            zd[rg * 2 + 0] = p0 * dr;
            zd[rg * 2 + 1] = p1 * dr;
        }
    }
}

// ---------------- Layer-3 aggregation on zd (premultiplied), 4 lanes/node, -> atomic pool
// az_i = zd_i*di + di * Σ_j zd_j ;  pooled per graph.

__global__ void k_aggz(const float* __restrict__ zd, const int* __restrict__ rowptr,
                       const int* __restrict__ csr, const float* __restrict__ dinv,
                       const int* __restrict__ batch, float* __restrict__ pool) {
    int tid = blockIdx.x * 256 + threadIdx.x;
    int i = tid >> 2, sub = tid & 3;
    if (i >= N_NODES) return;
    const float2* Z = (const float2*)zd;
    int e0 = rowptr[i], e1 = rowptr[i + 1];
    float a0 = 0.f, a1 = 0.f;
    for (int e = e0 + sub; e < e1; e += 4) {
        float2 zj = Z[csr[e]];
        a0 += zj.x; a1 += zj.y;
    }
    a0 += __shfl_xor(a0, 1); a1 += __shfl_xor(a1, 1);
    a0 += __shfl_xor(a0, 2); a1 += __shfl_xor(a1, 2);
    if (sub == 0) {
        float di = dinv[i];
        float2 zi = Z[i];
        float r0 = (zi.x + a0) * di;   // zd_i*di + di*Σ zd_j
        float r1 = (zi.y + a1) * di;
        int g = batch[i];
        atomicAdd(&pool[g * 2 + 0], r0);
        atomicAdd(&pool[g * 2 + 1], r1);
    }
}

// ---------------- Final: mean + consts (batch sorted; counts via binary search) ----------------

__global__ __launch_bounds__(256) void k_final3(const float* __restrict__ pool,
                                                const int* __restrict__ batch,
                                                const float* __restrict__ w3buf,
                                                float* __restrict__ out) {
    int g = blockIdx.x * 256 + threadIdx.x;
    if (g >= NG) return;
    int lo = 0, hi = N_NODES;
    while (lo < hi) { int mid = (lo + hi) >> 1; if (batch[mid] < g) lo = mid + 1; else hi = mid; }
    int start = lo;
    hi = N_NODES;
    while (lo < hi) { int mid = (lo + hi) >> 1; if (batch[mid] < g + 1) lo = mid + 1; else hi = mid; }
    int end = lo;
    if (end > start) {
        float inv = 1.0f / (float)(end - start);
        out[g * 2 + 0] = pool[g * 2 + 0] * inv + w3buf[256];
        out[g * 2 + 1] = pool[g * 2 + 1] * inv + w3buf[257];
    } else {
        out[g * 2 + 0] = w3buf[258];
        out[g * 2 + 1] = w3buf[259];
    }
}

// ---------------- launch ----------------

extern "C" void kernel_launch(void* const* d_in, const int* in_sizes, int n_in,
                              void* d_out, int out_size, void* d_ws, size_t ws_size,
                              hipStream_t stream) {
    const float* x    = (const float*)d_in[0];
    const float* W1   = (const float*)d_in[1];
    const float* b1   = (const float*)d_in[2];
    const float* W2   = (const float*)d_in[3];
    const float* b2   = (const float*)d_in[4];
    const float* W3   = (const float*)d_in[5];
    const float* b3   = (const float*)d_in[6];
    const float* Wlin = (const float*)d_in[7];
    const float* blin = (const float*)d_in[8];
    const int*   eidx = (const int*)d_in[9];
    const int*   batch= (const int*)d_in[10];
    const int* esrc = eidx;
    const int* edst = eidx + N_EDGES;
    float* out = (float*)d_out;

    char* w = (char*)d_ws;
    size_t off = 0;
    auto alloc = [&](size_t bytes) { size_t o = off; off = (off + bytes + 255) & ~(size_t)255; return o; };
    // cnt and pool adjacent -> one memset zeroes both
    size_t cnt_off = alloc(N_NODES * 4);
    int*   cnt    = (int*)  (w + cnt_off);
    float* pool   = (float*)(w + alloc(NG * 2 * 4));
    size_t zero_bytes = off - cnt_off;
    int*   rowptr = (int*)  (w + alloc((N_NODES + 1) * 4));
    int*   csr    = (int*)  (w + alloc(N_EDGES * 4));
    int*   pos    = (int*)  (w + alloc(N_EDGES * 4));
    float* dinv   = (float*)(w + alloc(N_NODES * 4));
    float* xd     = (float*)(w + alloc(N_NODES * 4));
    float2* s1d   = (float2*)(w + alloc((size_t)N_NODES * 8));
    int*   bsum   = (int*)  (w + alloc(NB_SCAN * 4));
    float* w3buf  = (float*)(w + alloc(260 * 4));
    float* zd     = (float*)(w + alloc((size_t)N_NODES * 2 * 4));

    const int FB = (N_EDGES + 255) / 256;       // 2344
    const int QB = (N_NODES * 4 + 255) / 256;   // 782 (4 lanes/node)
    // 1: zero cnt + pool
    hipMemsetAsync(cnt, 0, zero_bytes, stream);
    // 2: degree count + pos + w3lin precompute (extra block)
    k_count<<<EB, 256, 0, stream>>>(edst, cnt, pos, W3, Wlin, b3, blin, w3buf);
    // 3: per-256-chunk sums
    k_blocksum<<<NB_SCAN, 256, 0, stream>>>(cnt, bsum);
    // 4: rowptr + dinv + xd
    k_rowptr<<<NB_SCAN, 256, 0, stream>>>(cnt, bsum, x, rowptr, dinv, xd);
    // 5: CSR fill (atomic-free)
    k_fill<<<FB, 256, 0, stream>>>(esrc, edst, rowptr, pos, csr);
    // 6: layer-1 scalar aggregate (4 lanes/node)
    k_s1d<<<QB, 256, 0, stream>>>(x, xd, dinv, rowptr, csr, s1d);
    // 7: fused reconstruct + GEMM + relu + projection -> zd [N,2]  (32-row tiles, LDS dedup)
    k_gemm_fused<<<(N_NODES + 31) / 32, 256, 0, stream>>>(s1d, rowptr, csr,
                                                          W1, b1, W2, b2, w3buf, zd);
    // 8: layer-3 aggregation on zd (4 lanes/node) + atomic pool
    k_aggz<<<QB, 256, 0, stream>>>(zd, rowptr, csr, dinv, batch, pool);
    // 9: mean + consts
    k_final3<<<2, 256, 0, stream>>>(pool, batch, w3buf, out);
}